// Round 2
// baseline (4911.460 us; speedup 1.0000x reference)
//
#include <hip/hip_runtime.h>
#include <cstdint>
#include <cstddef>

#define NN 50000
#define NE 400000
#define NG 256
#define DIM 200
#define NSTEPS 6

// ---------------- utility kernels ----------------
__global__ void k_copy_f4(const float4* __restrict__ a, float4* __restrict__ b, int n4) {
  for (int i = blockIdx.x * blockDim.x + threadIdx.x; i < n4; i += gridDim.x * blockDim.x)
    b[i] = a[i];
}

__global__ void k_zero_i32(int* __restrict__ p, int n) {
  for (int i = blockIdx.x * blockDim.x + threadIdx.x; i < n; i += gridDim.x * blockDim.x)
    p[i] = 0;
}

__global__ void k_zero_f32(float* __restrict__ p, int n) {
  for (int i = blockIdx.x * blockDim.x + threadIdx.x; i < n; i += gridDim.x * blockDim.x)
    p[i] = 0.f;
}

__global__ void k_copy_i32(const int* __restrict__ a, int* __restrict__ b, int n) {
  for (int i = blockIdx.x * blockDim.x + threadIdx.x; i < n; i += gridDim.x * blockDim.x)
    b[i] = a[i];
}

__global__ void k_hist(const int* __restrict__ dst, int* __restrict__ cnt, int nE) {
  int e = blockIdx.x * blockDim.x + threadIdx.x;
  if (e < nE) atomicAdd(&cnt[dst[e]], 1);
}

// single-block scan: off[0]=0, off[i+1]=sum cnt[0..i]
__global__ void k_scan(const int* __restrict__ cnt, int* __restrict__ off, int n) {
  __shared__ int buf[1024];
  __shared__ int carry;
  int tid = threadIdx.x;
  if (tid == 0) { carry = 0; off[0] = 0; }
  __syncthreads();
  for (int base = 0; base < n; base += 1024) {
    int i = base + tid;
    int v = (i < n) ? cnt[i] : 0;
    buf[tid] = v;
    __syncthreads();
    for (int d = 1; d < 1024; d <<= 1) {
      int t = (tid >= d) ? buf[tid - d] : 0;
      __syncthreads();
      buf[tid] += t;
      __syncthreads();
    }
    if (i < n) off[i + 1] = carry + buf[tid];
    __syncthreads();
    if (tid == 0) carry += buf[1023];
    __syncthreads();
  }
}

__global__ void k_scatter(const int* __restrict__ dst, int* __restrict__ cursor,
                          int* __restrict__ elist, int nE) {
  int e = blockIdx.x * blockDim.x + threadIdx.x;
  if (e < nE) {
    int d = dst[e];
    int pos = atomicAdd(&cursor[d], 1);
    elist[pos] = e;
  }
}

// ---------------- tiled fp32 GEMM: C[M,N] = A[M,K] * op(B) ----------------
// TB=false: B is [K,N]. TB=true: B is [N,K] (compute A*B^T).
#define GBM 64
#define GBN 64
#define GBK 8

template <bool TB>
__global__ __launch_bounds__(256) void k_gemm(const float* __restrict__ A,
                                              const float* __restrict__ B,
                                              float* __restrict__ C,
                                              int M, int N, int K) {
  __shared__ __align__(16) float As[GBK][GBM];
  __shared__ __align__(16) float Bs[GBK][GBN];
  int tid = threadIdx.x;
  int row0 = blockIdx.y * GBM;
  int col0 = blockIdx.x * GBN;
  int ty = tid >> 4, tx = tid & 15;
  float acc[4][4] = {};

  for (int k0 = 0; k0 < K; k0 += GBK) {
    {
      int r = tid >> 2;
      int kk = (tid & 3) * 2;
      int gr = row0 + r;
      float2 v = make_float2(0.f, 0.f);
      if (gr < M) v = *reinterpret_cast<const float2*>(&A[(size_t)gr * K + k0 + kk]);
      As[kk][r] = v.x;
      As[kk + 1][r] = v.y;
    }
    if (!TB) {
      int k = tid >> 5;
      int n = (tid & 31) * 2;
      int gn = col0 + n;
      float2 v = make_float2(0.f, 0.f);
      if (gn + 1 < N) v = *reinterpret_cast<const float2*>(&B[(size_t)(k0 + k) * N + gn]);
      else if (gn < N) v.x = B[(size_t)(k0 + k) * N + gn];
      Bs[k][n] = v.x;
      Bs[k][n + 1] = v.y;
    } else {
      int n = tid >> 2;
      int kk = (tid & 3) * 2;
      int gn = col0 + n;
      float2 v = make_float2(0.f, 0.f);
      if (gn < N) v = *reinterpret_cast<const float2*>(&B[(size_t)gn * K + k0 + kk]);
      Bs[kk][n] = v.x;
      Bs[kk + 1][n] = v.y;
    }
    __syncthreads();
#pragma unroll
    for (int k = 0; k < GBK; ++k) {
      float4 av = *reinterpret_cast<const float4*>(&As[k][ty * 4]);
      float4 bv = *reinterpret_cast<const float4*>(&Bs[k][tx * 4]);
      float a[4] = {av.x, av.y, av.z, av.w};
      float b[4] = {bv.x, bv.y, bv.z, bv.w};
#pragma unroll
      for (int i = 0; i < 4; ++i)
#pragma unroll
        for (int j = 0; j < 4; ++j) acc[i][j] += a[i] * b[j];
    }
    __syncthreads();
  }

#pragma unroll
  for (int i = 0; i < 4; ++i) {
    int r = row0 + ty * 4 + i;
    if (r >= M) continue;
#pragma unroll
    for (int j = 0; j < 4; ++j) {
      int c = col0 + tx * 4 + j;
      if (c < N) C[(size_t)r * N + c] = acc[i][j];
    }
  }
}

// ---------------- aggregation: aggH[i] = sum_{e: dst[e]==i} h[src[e]] ----------------
__global__ __launch_bounds__(256) void k_aggregate(const float* __restrict__ h,
                                                   const int* __restrict__ off,
                                                   const int* __restrict__ elist,
                                                   const int* __restrict__ src,
                                                   float* __restrict__ aggH) {
  int i = blockIdx.x;
  int j = threadIdx.x;
  int beg = off[i], end = off[i + 1];
  float acc = 0.f;
  for (int p = beg; p < end; ++p) {
    int e = elist[p];
    int s = src[e];
    if (j < DIM) acc += h[(size_t)s * DIM + j];
  }
  if (j < DIM) aggH[(size_t)i * DIM + j] = acc;
}

// ---------------- fused: gi = aggH@Wc + b_ih; gh = h@w_hh^T + b_hh; GRU -> hnext ----
// Wc is [D, 3D] row-major (= W_s @ w_ih^T). w_hh is [3D, D] row-major.
#define FBM 64
#define FBN 64
#define FBK 8

__global__ __launch_bounds__(256) void k_fused_gru(
    const float* __restrict__ aggH, const float* __restrict__ h,
    const float* __restrict__ Wc, const float* __restrict__ w_hh,
    const float* __restrict__ b_ih, const float* __restrict__ b_hh,
    float* __restrict__ hnext) {
  __shared__ __align__(16) float As[FBK][FBM];
  __shared__ __align__(16) float Hs[FBK][FBM];
  __shared__ __align__(16) float B1[3][FBK][FBN];
  __shared__ __align__(16) float B2[3][FBK][FBN];
  int tid = threadIdx.x;
  int row0 = blockIdx.y * FBM;
  int col0 = blockIdx.x * FBN;
  int ty = tid >> 4, tx = tid & 15;
  float ai[3][4][4] = {};
  float ah[3][4][4] = {};

  for (int k0 = 0; k0 < DIM; k0 += FBK) {
    {
      int r = tid >> 2;
      int kk = (tid & 3) * 2;
      int gr = row0 + r;
      float2 va = make_float2(0.f, 0.f), vh = make_float2(0.f, 0.f);
      if (gr < NN) {
        va = *reinterpret_cast<const float2*>(&aggH[(size_t)gr * DIM + k0 + kk]);
        vh = *reinterpret_cast<const float2*>(&h[(size_t)gr * DIM + k0 + kk]);
      }
      As[kk][r] = va.x; As[kk + 1][r] = va.y;
      Hs[kk][r] = vh.x; Hs[kk + 1][r] = vh.y;
    }
    {
      // B1[g][k][n] = Wc[(k0+k)*600 + g*200 + col0 + n] (contig in n)
      int k = tid >> 5;
      int n = (tid & 31) * 2;
      int cg = col0 + n;
#pragma unroll
      for (int g = 0; g < 3; ++g) {
        float2 v = make_float2(0.f, 0.f);
        if (cg < DIM)
          v = *reinterpret_cast<const float2*>(&Wc[(size_t)(k0 + k) * (3 * DIM) + g * DIM + cg]);
        B1[g][k][n] = v.x;
        B1[g][k][n + 1] = v.y;
      }
    }
    {
      // B2[g][k][n] = w_hh[(g*200 + col0 + n)*200 + k0 + k] (contig in k)
      int n = tid >> 2;
      int kk = (tid & 3) * 2;
      int cg = col0 + n;
#pragma unroll
      for (int g = 0; g < 3; ++g) {
        float2 v = make_float2(0.f, 0.f);
        if (cg < DIM)
          v = *reinterpret_cast<const float2*>(&w_hh[(size_t)(g * DIM + cg) * DIM + k0 + kk]);
        B2[g][kk][n] = v.x;
        B2[g][kk + 1][n] = v.y;
      }
    }
    __syncthreads();
#pragma unroll
    for (int k = 0; k < FBK; ++k) {
      float4 av = *reinterpret_cast<const float4*>(&As[k][ty * 4]);
      float4 hv = *reinterpret_cast<const float4*>(&Hs[k][ty * 4]);
      float a[4] = {av.x, av.y, av.z, av.w};
      float hh[4] = {hv.x, hv.y, hv.z, hv.w};
#pragma unroll
      for (int g = 0; g < 3; ++g) {
        float4 b1v = *reinterpret_cast<const float4*>(&B1[g][k][tx * 4]);
        float4 b2v = *reinterpret_cast<const float4*>(&B2[g][k][tx * 4]);
        float b1[4] = {b1v.x, b1v.y, b1v.z, b1v.w};
        float b2[4] = {b2v.x, b2v.y, b2v.z, b2v.w};
#pragma unroll
        for (int i = 0; i < 4; ++i)
#pragma unroll
          for (int j = 0; j < 4; ++j) {
            ai[g][i][j] += a[i] * b1[j];
            ah[g][i][j] += hh[i] * b2[j];
          }
      }
    }
    __syncthreads();
  }

#pragma unroll
  for (int i = 0; i < 4; ++i) {
    int r = row0 + ty * 4 + i;
    if (r >= NN) continue;
#pragma unroll
    for (int j = 0; j < 4; ++j) {
      int c = col0 + tx * 4 + j;
      if (c >= DIM) continue;
      float gir = ai[0][i][j] + b_ih[c];
      float giz = ai[1][i][j] + b_ih[DIM + c];
      float gin = ai[2][i][j] + b_ih[2 * DIM + c];
      float ghr = ah[0][i][j] + b_hh[c];
      float ghz = ah[1][i][j] + b_hh[DIM + c];
      float ghn = ah[2][i][j] + b_hh[2 * DIM + c];
      float rr = 1.f / (1.f + expf(-(gir + ghr)));
      float zz = 1.f / (1.f + expf(-(giz + ghz)));
      float nn = tanhf(gin + rr * ghn);
      float hv = h[(size_t)r * DIM + c];
      hnext[(size_t)r * DIM + c] = (1.f - zz) * nn + zz * hv;
    }
  }
}

// ---------------- relu + segment_max pooling ----------------
__global__ __launch_bounds__(256) void k_pool(const float* __restrict__ h,
                                              const int* __restrict__ batch,
                                              float* __restrict__ pooled) {
  int i = blockIdx.x;
  int j = threadIdx.x;
  if (j < DIM) {
    int g = batch[i];
    float v = h[(size_t)i * DIM + j];
    v = v > 0.f ? v : 0.f;
    atomicMax((int*)&pooled[(size_t)g * DIM + j], __float_as_int(v));
  }
}

// ---------------- classifier: sigmoid(pooled @ cls_w^T + cls_b) ----------------
__global__ __launch_bounds__(256) void k_classify(const float* __restrict__ pooled,
                                                  const float* __restrict__ w,
                                                  const float* __restrict__ b,
                                                  float* __restrict__ out) {
  __shared__ float r0[256], r1[256];
  int g = blockIdx.x;
  int j = threadIdx.x;
  float p = (j < DIM) ? pooled[(size_t)g * DIM + j] : 0.f;
  r0[j] = (j < DIM) ? p * w[j] : 0.f;
  r1[j] = (j < DIM) ? p * w[DIM + j] : 0.f;
  __syncthreads();
  for (int d = 128; d > 0; d >>= 1) {
    if (j < d) { r0[j] += r0[j + d]; r1[j] += r1[j + d]; }
    __syncthreads();
  }
  if (j == 0) {
    out[g * 2 + 0] = 1.f / (1.f + expf(-(r0[0] + b[0])));
    out[g * 2 + 1] = 1.f / (1.f + expf(-(r1[0] + b[1])));
  }
}

// ---------------- host ----------------
extern "C" void kernel_launch(void* const* d_in, const int* in_sizes, int n_in,
                              void* d_out, int out_size, void* d_ws, size_t ws_size,
                              hipStream_t stream) {
  const float* x = (const float*)d_in[0];
  const int* edge_index = (const int*)d_in[1];
  const int* batch = (const int*)d_in[2];
  const float* ggnn_w = (const float*)d_in[3];
  const float* w_ih = (const float*)d_in[4];
  const float* w_hh = (const float*)d_in[5];
  const float* b_ih = (const float*)d_in[6];
  const float* b_hh = (const float*)d_in[7];
  const float* cls_w = (const float*)d_in[8];
  const float* cls_b = (const float*)d_in[9];
  float* out = (float*)d_out;

  const int* src = edge_index;       // edge_index[0]
  const int* dst = edge_index + NE;  // edge_index[1]

  // workspace carve (~125 MB total)
  char* wsb = (char*)d_ws;
  size_t off = 0;
  auto alloc = [&](size_t bytes) -> void* {
    void* p = wsb + off;
    off += (bytes + 255) & ~(size_t)255;
    return p;
  };
  float* hA = (float*)alloc((size_t)NN * DIM * 4);          // 40 MB
  float* hB = (float*)alloc((size_t)NN * DIM * 4);          // 40 MB
  float* aggH = (float*)alloc((size_t)NN * DIM * 4);        // 40 MB
  float* Wc = (float*)alloc((size_t)NSTEPS * DIM * 3 * DIM * 4);  // 2.88 MB
  float* pooled = (float*)alloc((size_t)NG * DIM * 4);
  int* indeg = (int*)alloc((size_t)NN * 4);
  int* offs = (int*)alloc((size_t)(NN + 1) * 4);
  int* elist = (int*)alloc((size_t)NE * 4);
  if (off > ws_size) return;  // undersized workspace -> clean absmax failure, not a fault

  // h0 = x
  k_copy_f4<<<2048, 256, 0, stream>>>((const float4*)x, (float4*)hA, NN * DIM / 4);

  // CSR build (dst -> edge list)
  k_zero_i32<<<196, 256, 0, stream>>>(indeg, NN);
  k_hist<<<(NE + 255) / 256, 256, 0, stream>>>(dst, indeg, NE);
  k_scan<<<1, 1024, 0, stream>>>(indeg, offs, NN);
  k_copy_i32<<<196, 256, 0, stream>>>(offs, indeg, NN);
  k_scatter<<<(NE + 255) / 256, 256, 0, stream>>>(dst, indeg, elist, NE);

  // Wc[s] = ggnn_w[s] @ w_ih^T  ([200,200]x[600,200]^T -> [200,600])
  {
    dim3 g((3 * DIM + GBN - 1) / GBN, (DIM + GBM - 1) / GBM);
    for (int s = 0; s < NSTEPS; ++s)
      k_gemm<true><<<g, 256, 0, stream>>>(ggnn_w + (size_t)s * DIM * DIM, w_ih,
                                          Wc + (size_t)s * DIM * 3 * DIM, DIM, 3 * DIM, DIM);
  }

  dim3 fgrid((DIM + FBN - 1) / FBN, (NN + FBM - 1) / FBM);  // 4 x 782
  float* hcur = hA;
  float* hnext = hB;
  for (int s = 0; s < NSTEPS; ++s) {
    k_aggregate<<<NN, 256, 0, stream>>>(hcur, offs, elist, src, aggH);
    k_fused_gru<<<fgrid, 256, 0, stream>>>(aggH, hcur, Wc + (size_t)s * DIM * 3 * DIM,
                                           w_hh, b_ih, b_hh, hnext);
    float* t = hcur; hcur = hnext; hnext = t;
  }

  k_zero_f32<<<200, 256, 0, stream>>>(pooled, NG * DIM);
  k_pool<<<NN, 256, 0, stream>>>(hcur, batch, pooled);
  k_classify<<<NG, 256, 0, stream>>>(pooled, cls_w, cls_b, out);
}

// Round 3
// 2143.502 us; speedup vs baseline: 2.2913x; 2.2913x over previous
//
#include <hip/hip_runtime.h>
#include <cstdint>
#include <cstddef>

#define NN 50000
#define NE 400000
#define NG 256
#define DIM 200
#define NSTEPS 6

typedef unsigned int uint;
typedef __attribute__((ext_vector_type(8))) short short8;
typedef __attribute__((ext_vector_type(4))) short short4v;
typedef __attribute__((ext_vector_type(4))) float f32x4;

// ---- packed split-bf16 helpers: word = (hi_bf16 << 16) | lo_bf16 ----
__device__ __forceinline__ float up_hi(uint w) { return __uint_as_float(w & 0xffff0000u); }
__device__ __forceinline__ float up_lo(uint w) { return __uint_as_float(w << 16); }
__device__ __forceinline__ float up_f(uint w) { return up_hi(w) + up_lo(w); }
__device__ __forceinline__ uint packf(float v) {
  uint u = __float_as_uint(v);
  uint t = u + 0x7fffu + ((u >> 16) & 1u);   // RN-even to bf16
  uint hb = t & 0xffff0000u;
  float lo = v - __uint_as_float(hb);
  uint ul = __float_as_uint(lo);
  uint t2 = ul + 0x7fffu + ((ul >> 16) & 1u);
  return hb | (t2 >> 16);
}

// ---------------- utility kernels ----------------
__global__ void k_zero_i32(int* __restrict__ p, int n) {
  for (int i = blockIdx.x * blockDim.x + threadIdx.x; i < n; i += gridDim.x * blockDim.x)
    p[i] = 0;
}
__global__ void k_zero_f32(float* __restrict__ p, int n) {
  for (int i = blockIdx.x * blockDim.x + threadIdx.x; i < n; i += gridDim.x * blockDim.x)
    p[i] = 0.f;
}
__global__ void k_copy_i32(const int* __restrict__ a, int* __restrict__ b, int n) {
  for (int i = blockIdx.x * blockDim.x + threadIdx.x; i < n; i += gridDim.x * blockDim.x)
    b[i] = a[i];
}
__global__ void k_hist(const int* __restrict__ dst, int* __restrict__ cnt, int nE) {
  int e = blockIdx.x * blockDim.x + threadIdx.x;
  if (e < nE) atomicAdd(&cnt[dst[e]], 1);
}
__global__ void k_scan(const int* __restrict__ cnt, int* __restrict__ off, int n) {
  __shared__ int buf[1024];
  __shared__ int carry;
  int tid = threadIdx.x;
  if (tid == 0) { carry = 0; off[0] = 0; }
  __syncthreads();
  for (int base = 0; base < n; base += 1024) {
    int i = base + tid;
    int v = (i < n) ? cnt[i] : 0;
    buf[tid] = v;
    __syncthreads();
    for (int d = 1; d < 1024; d <<= 1) {
      int t = (tid >= d) ? buf[tid - d] : 0;
      __syncthreads();
      buf[tid] += t;
      __syncthreads();
    }
    if (i < n) off[i + 1] = carry + buf[tid];
    __syncthreads();
    if (tid == 0) carry += buf[1023];
    __syncthreads();
  }
}
__global__ void k_scatter(const int* __restrict__ dst, int* __restrict__ cursor,
                          int* __restrict__ elist, int nE) {
  int e = blockIdx.x * blockDim.x + threadIdx.x;
  if (e < nE) {
    int d = dst[e];
    int pos = atomicAdd(&cursor[d], 1);
    elist[pos] = e;
  }
}

// pack fp32 array -> packed split-bf16 (vectorized)
__global__ void k_pack_f32(const float4* __restrict__ in, uint4* __restrict__ out, int n4) {
  for (int i = blockIdx.x * blockDim.x + threadIdx.x; i < n4; i += gridDim.x * blockDim.x) {
    float4 v = in[i];
    uint4 o;
    o.x = packf(v.x); o.y = packf(v.y); o.z = packf(v.z); o.w = packf(v.w);
    out[i] = o;
  }
}

// transpose+pack: Wc fp32 [200][600] -> WcT_pk uint [600][200]
__global__ void k_pack_wcT(const float* __restrict__ Wc, uint* __restrict__ out) {
  int idx = blockIdx.x * blockDim.x + threadIdx.x;
  if (idx < 600 * DIM) {
    int c = idx / DIM, k = idx - c * DIM;
    out[idx] = packf(Wc[(size_t)k * 600 + c]);
  }
}

// ---------------- fp32 GEMM (tiny, for Wc = W @ w_ih^T) ----------------
#define GBM 64
#define GBN 64
#define GBK 8
__global__ __launch_bounds__(256) void k_gemm_bt(const float* __restrict__ A,
                                                 const float* __restrict__ B,
                                                 float* __restrict__ C,
                                                 int M, int N, int K) {
  __shared__ __align__(16) float As[GBK][GBM];
  __shared__ __align__(16) float Bs[GBK][GBN];
  int tid = threadIdx.x;
  int row0 = blockIdx.y * GBM;
  int col0 = blockIdx.x * GBN;
  int ty = tid >> 4, tx = tid & 15;
  float acc[4][4] = {};
  for (int k0 = 0; k0 < K; k0 += GBK) {
    {
      int r = tid >> 2;
      int kk = (tid & 3) * 2;
      int gr = row0 + r;
      float2 v = make_float2(0.f, 0.f);
      if (gr < M) v = *reinterpret_cast<const float2*>(&A[(size_t)gr * K + k0 + kk]);
      As[kk][r] = v.x; As[kk + 1][r] = v.y;
    }
    {
      int n = tid >> 2;
      int kk = (tid & 3) * 2;
      int gn = col0 + n;
      float2 v = make_float2(0.f, 0.f);
      if (gn < N) v = *reinterpret_cast<const float2*>(&B[(size_t)gn * K + k0 + kk]);
      Bs[kk][n] = v.x; Bs[kk + 1][n] = v.y;
    }
    __syncthreads();
#pragma unroll
    for (int k = 0; k < GBK; ++k) {
      float4 av = *reinterpret_cast<const float4*>(&As[k][ty * 4]);
      float4 bv = *reinterpret_cast<const float4*>(&Bs[k][tx * 4]);
      float a[4] = {av.x, av.y, av.z, av.w};
      float b[4] = {bv.x, bv.y, bv.z, bv.w};
#pragma unroll
      for (int i = 0; i < 4; ++i)
#pragma unroll
        for (int j = 0; j < 4; ++j) acc[i][j] += a[i] * b[j];
    }
    __syncthreads();
  }
#pragma unroll
  for (int i = 0; i < 4; ++i) {
    int r = row0 + ty * 4 + i;
    if (r >= M) continue;
#pragma unroll
    for (int j = 0; j < 4; ++j) {
      int c = col0 + tx * 4 + j;
      if (c < N) C[(size_t)r * N + c] = acc[i][j];
    }
  }
}

// ---------------- aggregation: wave per node, packed io ----------------
__global__ __launch_bounds__(256) void k_aggregate_pk(const uint* __restrict__ hpk,
                                                      const int* __restrict__ off,
                                                      const int* __restrict__ elist,
                                                      const int* __restrict__ src,
                                                      uint* __restrict__ aggpk) {
  int node = blockIdx.x * 4 + (threadIdx.x >> 6);
  if (node >= NN) return;
  int lane = threadIdx.x & 63;
  float a0 = 0.f, a1 = 0.f, a2 = 0.f, a3 = 0.f;
  int beg = off[node], end = off[node + 1];
  for (int p = beg; p < end; ++p) {
    int s = src[elist[p]];
    const uint* hr = hpk + (size_t)s * DIM;
    uint w0 = hr[lane];
    uint w1 = hr[lane + 64];
    uint w2 = hr[lane + 128];
    a0 += up_f(w0);
    a1 += up_f(w1);
    a2 += up_f(w2);
    if (lane < 8) a3 += up_f(hr[lane + 192]);
  }
  uint* ar = aggpk + (size_t)node * DIM;
  ar[lane] = packf(a0);
  ar[lane + 64] = packf(a1);
  ar[lane + 128] = packf(a2);
  if (lane < 8) ar[lane + 192] = packf(a3);
}

// ---------------- fused MFMA GRU step ----------------
// gi = aggH @ Wc + b_ih ; gh = h @ w_hh^T + b_hh ; hnext = GRU(gi, gh, h)
// A (aggH,h): packed uint [NN][200]. B: WcT_pk/whT_pk packed uint [600][200].
// Split-bf16 3-pass per product. Block: 64 rows x 32 cols, 4 waves, KT=32.
#define KT 32
#define NKT 7   // 7*32 = 224 >= 200 (zero-padded)

__global__ __launch_bounds__(256) void k_fused_mfma(
    const uint* __restrict__ aggpk, const uint* __restrict__ hpk,
    const uint* __restrict__ wcT, const uint* __restrict__ whT,
    const float* __restrict__ b_ih, const float* __restrict__ b_hh,
    uint* __restrict__ hnextpk) {
  // LDS: stride 40 shorts (80B) keeps ds_read_b128 bank-balanced, 16B-aligned
  __shared__ short Ah[2][64][40];   // [mat 0=agg,1=h][row][k] hi
  __shared__ short Al[2][64][40];   // lo
  __shared__ short Bh[6][32][40];   // [gate*2 + (0=Wc,1=whT)][col][k] hi
  __shared__ short Bl[6][32][40];

  int tid = threadIdx.x;
  int lane = tid & 63;
  int wv = tid >> 6;
  int row0 = blockIdx.y * 64;
  int cc0 = blockIdx.x * 32;

  f32x4 ai[3][2] = {};
  f32x4 ah[3][2] = {};

  int lr = lane & 15;
  int lk = (lane >> 4) * 8;

  for (int t = 0; t < NKT; ++t) {
    int kt = t * KT;
    // ---- stage A: 2 mats x 64 rows x 32 k packed = 1024 uint4 chunks ----
#pragma unroll
    for (int rep = 0; rep < 4; ++rep) {
      int id = tid + rep * 256;
      int mat = id >> 9;
      int rem = id & 511;
      int row = rem >> 3;
      int k = (rem & 7) * 4;
      int gr = row0 + row;
      int gk = kt + k;
      bool valid = (gr < NN) && (gk < DIM);
      const uint* srcp = (mat ? hpk : aggpk) + (size_t)gr * DIM + gk;
      uint4 u = valid ? *reinterpret_cast<const uint4*>(srcp) : make_uint4(0, 0, 0, 0);
      short4v hs = {(short)(u.x >> 16), (short)(u.y >> 16), (short)(u.z >> 16), (short)(u.w >> 16)};
      short4v ls = {(short)(u.x & 0xffff), (short)(u.y & 0xffff), (short)(u.z & 0xffff), (short)(u.w & 0xffff)};
      *reinterpret_cast<short4v*>(&Ah[mat][row][k]) = hs;
      *reinterpret_cast<short4v*>(&Al[mat][row][k]) = ls;
    }
    // ---- stage B: 6 mats x 32 cols x 32 k = 1536 uint4 chunks ----
#pragma unroll
    for (int rep = 0; rep < 6; ++rep) {
      int id = tid + rep * 256;
      int mat = id >> 8;          // 0..5 = gate*2 + which
      int rem = id & 255;
      int col = rem >> 3;
      int k = (rem & 7) * 4;
      int g = mat >> 1;
      int which = mat & 1;
      int gcol = g * DIM + cc0 + col;
      int gk = kt + k;
      bool valid = (cc0 + col < DIM) && (gk < DIM);
      const uint* srcp = (which ? whT : wcT) + (size_t)gcol * DIM + gk;
      uint4 u = valid ? *reinterpret_cast<const uint4*>(srcp) : make_uint4(0, 0, 0, 0);
      short4v hs = {(short)(u.x >> 16), (short)(u.y >> 16), (short)(u.z >> 16), (short)(u.w >> 16)};
      short4v ls = {(short)(u.x & 0xffff), (short)(u.y & 0xffff), (short)(u.z & 0xffff), (short)(u.w & 0xffff)};
      *reinterpret_cast<short4v*>(&Bh[mat][col][k]) = hs;
      *reinterpret_cast<short4v*>(&Bl[mat][col][k]) = ls;
    }
    __syncthreads();

    // ---- compute: A frags (row = wv*16 + lr, k = lk..lk+7) ----
    short8 agh = *reinterpret_cast<const short8*>(&Ah[0][wv * 16 + lr][lk]);
    short8 agl = *reinterpret_cast<const short8*>(&Al[0][wv * 16 + lr][lk]);
    short8 hh = *reinterpret_cast<const short8*>(&Ah[1][wv * 16 + lr][lk]);
    short8 hl = *reinterpret_cast<const short8*>(&Al[1][wv * 16 + lr][lk]);
#pragma unroll
    for (int g = 0; g < 3; ++g) {
#pragma unroll
      for (int ct = 0; ct < 2; ++ct) {
        short8 b1h = *reinterpret_cast<const short8*>(&Bh[g * 2 + 0][ct * 16 + lr][lk]);
        short8 b1l = *reinterpret_cast<const short8*>(&Bl[g * 2 + 0][ct * 16 + lr][lk]);
        short8 b2h = *reinterpret_cast<const short8*>(&Bh[g * 2 + 1][ct * 16 + lr][lk]);
        short8 b2l = *reinterpret_cast<const short8*>(&Bl[g * 2 + 1][ct * 16 + lr][lk]);
        ai[g][ct] = __builtin_amdgcn_mfma_f32_16x16x32_bf16(agh, b1h, ai[g][ct], 0, 0, 0);
        ai[g][ct] = __builtin_amdgcn_mfma_f32_16x16x32_bf16(agh, b1l, ai[g][ct], 0, 0, 0);
        ai[g][ct] = __builtin_amdgcn_mfma_f32_16x16x32_bf16(agl, b1h, ai[g][ct], 0, 0, 0);
        ah[g][ct] = __builtin_amdgcn_mfma_f32_16x16x32_bf16(hh, b2h, ah[g][ct], 0, 0, 0);
        ah[g][ct] = __builtin_amdgcn_mfma_f32_16x16x32_bf16(hh, b2l, ah[g][ct], 0, 0, 0);
        ah[g][ct] = __builtin_amdgcn_mfma_f32_16x16x32_bf16(hl, b2h, ah[g][ct], 0, 0, 0);
      }
    }
    __syncthreads();
  }

  // ---- epilogue: GRU gates, write packed hnext ----
#pragma unroll
  for (int ct = 0; ct < 2; ++ct) {
    int c = cc0 + ct * 16 + lr;
    if (c >= DIM) continue;
    float bir = b_ih[c], biz = b_ih[DIM + c], bin = b_ih[2 * DIM + c];
    float bhr = b_hh[c], bhz = b_hh[DIM + c], bhn = b_hh[2 * DIM + c];
#pragma unroll
    for (int q = 0; q < 4; ++q) {
      int r = row0 + wv * 16 + (lane >> 4) * 4 + q;
      if (r >= NN) continue;
      float gir = ai[0][ct][q] + bir;
      float giz = ai[1][ct][q] + biz;
      float gin = ai[2][ct][q] + bin;
      float ghr = ah[0][ct][q] + bhr;
      float ghz = ah[1][ct][q] + bhz;
      float ghn = ah[2][ct][q] + bhn;
      float rr = 1.f / (1.f + __expf(-(gir + ghr)));
      float zz = 1.f / (1.f + __expf(-(giz + ghz)));
      float nn = tanhf(gin + rr * ghn);
      float hv = up_f(hpk[(size_t)r * DIM + c]);
      hnextpk[(size_t)r * DIM + c] = packf((1.f - zz) * nn + zz * hv);
    }
  }
}

// ---------------- relu + segment_max pooling (packed h) ----------------
__global__ __launch_bounds__(256) void k_pool(const uint* __restrict__ hpk,
                                              const int* __restrict__ batch,
                                              float* __restrict__ pooled) {
  int i = blockIdx.x;
  int j = threadIdx.x;
  if (j < DIM) {
    int g = batch[i];
    float v = up_f(hpk[(size_t)i * DIM + j]);
    v = v > 0.f ? v : 0.f;
    atomicMax((int*)&pooled[(size_t)g * DIM + j], __float_as_int(v));
  }
}

__global__ __launch_bounds__(256) void k_classify(const float* __restrict__ pooled,
                                                  const float* __restrict__ w,
                                                  const float* __restrict__ b,
                                                  float* __restrict__ out) {
  __shared__ float r0[256], r1[256];
  int g = blockIdx.x;
  int j = threadIdx.x;
  float p = (j < DIM) ? pooled[(size_t)g * DIM + j] : 0.f;
  r0[j] = (j < DIM) ? p * w[j] : 0.f;
  r1[j] = (j < DIM) ? p * w[DIM + j] : 0.f;
  __syncthreads();
  for (int d = 128; d > 0; d >>= 1) {
    if (j < d) { r0[j] += r0[j + d]; r1[j] += r1[j + d]; }
    __syncthreads();
  }
  if (j == 0) {
    out[g * 2 + 0] = 1.f / (1.f + expf(-(r0[0] + b[0])));
    out[g * 2 + 1] = 1.f / (1.f + expf(-(r1[0] + b[1])));
  }
}

// ---------------- host ----------------
extern "C" void kernel_launch(void* const* d_in, const int* in_sizes, int n_in,
                              void* d_out, int out_size, void* d_ws, size_t ws_size,
                              hipStream_t stream) {
  const float* x = (const float*)d_in[0];
  const int* edge_index = (const int*)d_in[1];
  const int* batch = (const int*)d_in[2];
  const float* ggnn_w = (const float*)d_in[3];
  const float* w_ih = (const float*)d_in[4];
  const float* w_hh = (const float*)d_in[5];
  const float* b_ih = (const float*)d_in[6];
  const float* b_hh = (const float*)d_in[7];
  const float* cls_w = (const float*)d_in[8];
  const float* cls_b = (const float*)d_in[9];
  float* out = (float*)d_out;

  const int* src = edge_index;       // edge_index[0]
  const int* dst = edge_index + NE;  // edge_index[1]

  char* wsb = (char*)d_ws;
  size_t off = 0;
  auto alloc = [&](size_t bytes) -> void* {
    void* p = wsb + off;
    off += (bytes + 255) & ~(size_t)255;
    return p;
  };
  uint* hpkA = (uint*)alloc((size_t)NN * DIM * 4);   // 40 MB
  uint* hpkB = (uint*)alloc((size_t)NN * DIM * 4);   // 40 MB
  uint* aggpk = (uint*)alloc((size_t)NN * DIM * 4);  // 40 MB
  float* Wc_tmp = (float*)alloc((size_t)DIM * 3 * DIM * 4);        // 480 KB
  uint* wcT = (uint*)alloc((size_t)NSTEPS * 3 * DIM * DIM * 4);    // 2.88 MB
  uint* whT = (uint*)alloc((size_t)3 * DIM * DIM * 4);             // 480 KB
  float* pooled = (float*)alloc((size_t)NG * DIM * 4);
  int* indeg = (int*)alloc((size_t)NN * 4);
  int* offs = (int*)alloc((size_t)(NN + 1) * 4);
  int* elist = (int*)alloc((size_t)NE * 4);
  if (off > ws_size) return;  // fail loud (absmax) instead of faulting

  // h0 = pack(x)
  k_pack_f32<<<2048, 256, 0, stream>>>((const float4*)x, (uint4*)hpkA, NN * DIM / 4);

  // CSR build (dst -> edge list)
  k_zero_i32<<<196, 256, 0, stream>>>(indeg, NN);
  k_hist<<<(NE + 255) / 256, 256, 0, stream>>>(dst, indeg, NE);
  k_scan<<<1, 1024, 0, stream>>>(indeg, offs, NN);
  k_copy_i32<<<196, 256, 0, stream>>>(offs, indeg, NN);
  k_scatter<<<(NE + 255) / 256, 256, 0, stream>>>(dst, indeg, elist, NE);

  // weights: Wc[s] = ggnn_w[s] @ w_ih^T -> transpose+pack; whT = pack(w_hh)
  {
    dim3 g((3 * DIM + GBN - 1) / GBN, (DIM + GBM - 1) / GBM);
    for (int s = 0; s < NSTEPS; ++s) {
      k_gemm_bt<<<g, 256, 0, stream>>>(ggnn_w + (size_t)s * DIM * DIM, w_ih, Wc_tmp,
                                       DIM, 3 * DIM, DIM);
      k_pack_wcT<<<(600 * DIM + 255) / 256, 256, 0, stream>>>(
          Wc_tmp, wcT + (size_t)s * 3 * DIM * DIM);
    }
    k_pack_f32<<<512, 256, 0, stream>>>((const float4*)w_hh, (uint4*)whT, 3 * DIM * DIM / 4);
  }

  dim3 fgrid((DIM + 31) / 32, (NN + 63) / 64);  // 7 x 782
  uint* hcur = hpkA;
  uint* hnext = hpkB;
  for (int s = 0; s < NSTEPS; ++s) {
    k_aggregate_pk<<<(NN + 3) / 4, 256, 0, stream>>>(hcur, offs, elist, src, aggpk);
    k_fused_mfma<<<fgrid, 256, 0, stream>>>(aggpk, hcur, wcT + (size_t)s * 3 * DIM * DIM,
                                            whT, b_ih, b_hh, hnext);
    uint* t = hcur; hcur = hnext; hnext = t;
  }

  k_zero_f32<<<200, 256, 0, stream>>>(pooled, NG * DIM);
  k_pool<<<NN, 256, 0, stream>>>(hcur, batch, pooled);
  k_classify<<<NG, 256, 0, stream>>>(pooled, cls_w, cls_b, out);
}

// Round 4
// 1898.194 us; speedup vs baseline: 2.5874x; 1.1292x over previous
//
#include <hip/hip_runtime.h>
#include <cstdint>
#include <cstddef>

#define NN 50000
#define NE 400000
#define NG 256
#define DIM 200
#define NSTEPS 6

typedef unsigned int uint;
typedef __attribute__((ext_vector_type(8))) short short8;
typedef __attribute__((ext_vector_type(4))) short short4v;
typedef __attribute__((ext_vector_type(4))) float f32x4;

// ---- packed split-bf16 helpers: word = (hi_bf16 << 16) | lo_bf16 ----
__device__ __forceinline__ float up_hi(uint w) { return __uint_as_float(w & 0xffff0000u); }
__device__ __forceinline__ float up_lo(uint w) { return __uint_as_float(w << 16); }
__device__ __forceinline__ float up_f(uint w) { return up_hi(w) + up_lo(w); }
__device__ __forceinline__ uint packf(float v) {
  uint u = __float_as_uint(v);
  uint t = u + 0x7fffu + ((u >> 16) & 1u);   // RN-even to bf16
  uint hb = t & 0xffff0000u;
  float lo = v - __uint_as_float(hb);
  uint ul = __float_as_uint(lo);
  uint t2 = ul + 0x7fffu + ((ul >> 16) & 1u);
  return hb | (t2 >> 16);
}

// ---------------- utility kernels ----------------
__global__ void k_zero_i32(int* __restrict__ p, int n) {
  for (int i = blockIdx.x * blockDim.x + threadIdx.x; i < n; i += gridDim.x * blockDim.x)
    p[i] = 0;
}
__global__ void k_zero_f32(float* __restrict__ p, int n) {
  for (int i = blockIdx.x * blockDim.x + threadIdx.x; i < n; i += gridDim.x * blockDim.x)
    p[i] = 0.f;
}
__global__ void k_copy_i32(const int* __restrict__ a, int* __restrict__ b, int n) {
  for (int i = blockIdx.x * blockDim.x + threadIdx.x; i < n; i += gridDim.x * blockDim.x)
    b[i] = a[i];
}
__global__ void k_hist(const int* __restrict__ dst, int* __restrict__ cnt, int nE) {
  int e = blockIdx.x * blockDim.x + threadIdx.x;
  if (e < nE) atomicAdd(&cnt[dst[e]], 1);
}
__global__ void k_scan(const int* __restrict__ cnt, int* __restrict__ off, int n) {
  __shared__ int buf[1024];
  __shared__ int carry;
  int tid = threadIdx.x;
  if (tid == 0) { carry = 0; off[0] = 0; }
  __syncthreads();
  for (int base = 0; base < n; base += 1024) {
    int i = base + tid;
    int v = (i < n) ? cnt[i] : 0;
    buf[tid] = v;
    __syncthreads();
    for (int d = 1; d < 1024; d <<= 1) {
      int t = (tid >= d) ? buf[tid - d] : 0;
      __syncthreads();
      buf[tid] += t;
      __syncthreads();
    }
    if (i < n) off[i + 1] = carry + buf[tid];
    __syncthreads();
    if (tid == 0) carry += buf[1023];
    __syncthreads();
  }
}
// store src[e] directly (slist) - removes one indirection in aggregate
__global__ void k_scatter(const int* __restrict__ dst, const int* __restrict__ src,
                          int* __restrict__ cursor, int* __restrict__ slist, int nE) {
  int e = blockIdx.x * blockDim.x + threadIdx.x;
  if (e < nE) {
    int d = dst[e];
    int pos = atomicAdd(&cursor[d], 1);
    slist[pos] = src[e];
  }
}

// pack fp32 array -> packed split-bf16 (vectorized)
__global__ void k_pack_f32(const float4* __restrict__ in, uint4* __restrict__ out, int n4) {
  for (int i = blockIdx.x * blockDim.x + threadIdx.x; i < n4; i += gridDim.x * blockDim.x) {
    float4 v = in[i];
    uint4 o;
    o.x = packf(v.x); o.y = packf(v.y); o.z = packf(v.z); o.w = packf(v.w);
    out[i] = o;
  }
}

// transpose+pack: Wc fp32 [200][600] -> WcT_pk uint [600][200]
__global__ void k_pack_wcT(const float* __restrict__ Wc, uint* __restrict__ out) {
  int idx = blockIdx.x * blockDim.x + threadIdx.x;
  if (idx < 600 * DIM) {
    int c = idx / DIM, k = idx - c * DIM;
    out[idx] = packf(Wc[(size_t)k * 600 + c]);
  }
}

// ---------------- fp32 GEMM (tiny, for Wc = W @ w_ih^T) ----------------
#define GBM 64
#define GBN 64
#define GBK 8
__global__ __launch_bounds__(256) void k_gemm_bt(const float* __restrict__ A,
                                                 const float* __restrict__ B,
                                                 float* __restrict__ C,
                                                 int M, int N, int K) {
  __shared__ __align__(16) float As[GBK][GBM];
  __shared__ __align__(16) float Bs[GBK][GBN];
  int tid = threadIdx.x;
  int row0 = blockIdx.y * GBM;
  int col0 = blockIdx.x * GBN;
  int ty = tid >> 4, tx = tid & 15;
  float acc[4][4] = {};
  for (int k0 = 0; k0 < K; k0 += GBK) {
    {
      int r = tid >> 2;
      int kk = (tid & 3) * 2;
      int gr = row0 + r;
      float2 v = make_float2(0.f, 0.f);
      if (gr < M) v = *reinterpret_cast<const float2*>(&A[(size_t)gr * K + k0 + kk]);
      As[kk][r] = v.x; As[kk + 1][r] = v.y;
    }
    {
      int n = tid >> 2;
      int kk = (tid & 3) * 2;
      int gn = col0 + n;
      float2 v = make_float2(0.f, 0.f);
      if (gn < N) v = *reinterpret_cast<const float2*>(&B[(size_t)gn * K + k0 + kk]);
      Bs[kk][n] = v.x; Bs[kk + 1][n] = v.y;
    }
    __syncthreads();
#pragma unroll
    for (int k = 0; k < GBK; ++k) {
      float4 av = *reinterpret_cast<const float4*>(&As[k][ty * 4]);
      float4 bv = *reinterpret_cast<const float4*>(&Bs[k][tx * 4]);
      float a[4] = {av.x, av.y, av.z, av.w};
      float b[4] = {bv.x, bv.y, bv.z, bv.w};
#pragma unroll
      for (int i = 0; i < 4; ++i)
#pragma unroll
        for (int j = 0; j < 4; ++j) acc[i][j] += a[i] * b[j];
    }
    __syncthreads();
  }
#pragma unroll
  for (int i = 0; i < 4; ++i) {
    int r = row0 + ty * 4 + i;
    if (r >= M) continue;
#pragma unroll
    for (int j = 0; j < 4; ++j) {
      int c = col0 + tx * 4 + j;
      if (c < N) C[(size_t)r * N + c] = acc[i][j];
    }
  }
}

// ---------------- aggregation: wave per node, uint4 per lane ----------------
__global__ __launch_bounds__(256) void k_aggregate_pk(const uint* __restrict__ hpk,
                                                      const int* __restrict__ off,
                                                      const int* __restrict__ slist,
                                                      uint* __restrict__ aggpk) {
  int node = blockIdx.x * 4 + (threadIdx.x >> 6);
  if (node >= NN) return;
  int lane = threadIdx.x & 63;
  int c4 = lane * 4;
  bool act = c4 < DIM;
  float a0 = 0.f, a1 = 0.f, a2 = 0.f, a3 = 0.f;
  int beg = off[node], end = off[node + 1];
  int p = beg;
  for (; p + 1 < end; p += 2) {
    int s0 = slist[p];
    int s1 = slist[p + 1];
    if (act) {
      uint4 u0 = *reinterpret_cast<const uint4*>(hpk + (size_t)s0 * DIM + c4);
      uint4 u1 = *reinterpret_cast<const uint4*>(hpk + (size_t)s1 * DIM + c4);
      a0 += up_f(u0.x) + up_f(u1.x);
      a1 += up_f(u0.y) + up_f(u1.y);
      a2 += up_f(u0.z) + up_f(u1.z);
      a3 += up_f(u0.w) + up_f(u1.w);
    }
  }
  if (p < end) {
    int s = slist[p];
    if (act) {
      uint4 u = *reinterpret_cast<const uint4*>(hpk + (size_t)s * DIM + c4);
      a0 += up_f(u.x); a1 += up_f(u.y); a2 += up_f(u.z); a3 += up_f(u.w);
    }
  }
  if (act) {
    uint4 o;
    o.x = packf(a0); o.y = packf(a1); o.z = packf(a2); o.w = packf(a3);
    *reinterpret_cast<uint4*>(aggpk + (size_t)node * DIM + c4) = o;
  }
}

// ---------------- fused MFMA GRU step ----------------
// Block: 128 rows x 32 cols, 4 waves (wave = 32 rows, 2 row-frags). KT=32.
// 1D grid with bijective XCD swizzle: the 7 col-blocks of one row-panel run
// consecutively on the SAME XCD so the 205KB A-panel stays in its 4MB L2.
#define KT 32
#define NKT 7   // 7*32 = 224 >= 200 (zero-padded)
#define NRB ((NN + 127) / 128)   // 391
#define NCB 7

__global__ __launch_bounds__(256, 2) void k_fused_mfma(
    const uint* __restrict__ aggpk, const uint* __restrict__ hpk,
    const uint* __restrict__ wcT, const uint* __restrict__ whT,
    const float* __restrict__ b_ih, const float* __restrict__ b_hh,
    uint* __restrict__ hnextpk) {
  __shared__ short Ah[2][128][40];   // [mat 0=agg,1=h][row][k] hi (stride 80B, 16B-aligned)
  __shared__ short Al[2][128][40];
  __shared__ short Bh[6][32][40];    // [gate*2 + (0=Wc,1=whT)][col][k]
  __shared__ short Bl[6][32][40];

  int tid = threadIdx.x;
  int lane = tid & 63;
  int wv = tid >> 6;

  // XCD-aware bijective swizzle (m204): XCD x gets contiguous work chunk
  int nwg = NRB * NCB;            // 2737
  int q = nwg >> 3, r = nwg & 7;  // 342, 1
  int x = blockIdx.x & 7, ii = blockIdx.x >> 3;
  int work = (x < r ? x * (q + 1) : r * (q + 1) + (x - r) * q) + ii;
  int rb = work / NCB;
  int cb = work - rb * NCB;
  int row0 = rb * 128;
  int cc0 = cb * 32;

  f32x4 ai[3][2][2] = {};   // [gate][ct][rf]
  f32x4 ah[3][2][2] = {};

  int lr = lane & 15;
  int lk = (lane >> 4) * 8;

  for (int t = 0; t < NKT; ++t) {
    int kt = t * KT;
    // ---- stage A: 2 mats x 128 rows x 32 k = 2048 uint4 ----
#pragma unroll
    for (int rep = 0; rep < 8; ++rep) {
      int id = tid + rep * 256;
      int mat = id >> 10;
      int rem = id & 1023;
      int row = rem >> 3;
      int k = (rem & 7) * 4;
      int gr = row0 + row;
      int gk = kt + k;
      bool valid = (gr < NN) && (gk < DIM);
      const uint* srcp = (mat ? hpk : aggpk) + (size_t)gr * DIM + gk;
      uint4 u = valid ? *reinterpret_cast<const uint4*>(srcp) : make_uint4(0, 0, 0, 0);
      short4v hs = {(short)(u.x >> 16), (short)(u.y >> 16), (short)(u.z >> 16), (short)(u.w >> 16)};
      short4v ls = {(short)(u.x & 0xffff), (short)(u.y & 0xffff), (short)(u.z & 0xffff), (short)(u.w & 0xffff)};
      *reinterpret_cast<short4v*>(&Ah[mat][row][k]) = hs;
      *reinterpret_cast<short4v*>(&Al[mat][row][k]) = ls;
    }
    // ---- stage B: 6 mats x 32 cols x 32 k = 1536 uint4 ----
#pragma unroll
    for (int rep = 0; rep < 6; ++rep) {
      int id = tid + rep * 256;
      int mat = id >> 8;          // 0..5 = gate*2 + which
      int rem = id & 255;
      int col = rem >> 3;
      int k = (rem & 7) * 4;
      int g = mat >> 1;
      int which = mat & 1;
      int gcol = g * DIM + cc0 + col;
      int gk = kt + k;
      bool valid = (cc0 + col < DIM) && (gk < DIM);
      const uint* srcp = (which ? whT : wcT) + (size_t)gcol * DIM + gk;
      uint4 u = valid ? *reinterpret_cast<const uint4*>(srcp) : make_uint4(0, 0, 0, 0);
      short4v hs = {(short)(u.x >> 16), (short)(u.y >> 16), (short)(u.z >> 16), (short)(u.w >> 16)};
      short4v ls = {(short)(u.x & 0xffff), (short)(u.y & 0xffff), (short)(u.z & 0xffff), (short)(u.w & 0xffff)};
      *reinterpret_cast<short4v*>(&Bh[mat][col][k]) = hs;
      *reinterpret_cast<short4v*>(&Bl[mat][col][k]) = ls;
    }
    __syncthreads();

    // ---- compute: wave's rows = wv*32 + rf*16 + lr ----
    short8 agh0 = *reinterpret_cast<const short8*>(&Ah[0][wv * 32 + lr][lk]);
    short8 agh1 = *reinterpret_cast<const short8*>(&Ah[0][wv * 32 + 16 + lr][lk]);
    short8 agl0 = *reinterpret_cast<const short8*>(&Al[0][wv * 32 + lr][lk]);
    short8 agl1 = *reinterpret_cast<const short8*>(&Al[0][wv * 32 + 16 + lr][lk]);
    short8 hh0 = *reinterpret_cast<const short8*>(&Ah[1][wv * 32 + lr][lk]);
    short8 hh1 = *reinterpret_cast<const short8*>(&Ah[1][wv * 32 + 16 + lr][lk]);
    short8 hl0 = *reinterpret_cast<const short8*>(&Al[1][wv * 32 + lr][lk]);
    short8 hl1 = *reinterpret_cast<const short8*>(&Al[1][wv * 32 + 16 + lr][lk]);
#pragma unroll
    for (int g = 0; g < 3; ++g) {
#pragma unroll
      for (int ct = 0; ct < 2; ++ct) {
        short8 b1h = *reinterpret_cast<const short8*>(&Bh[g * 2 + 0][ct * 16 + lr][lk]);
        short8 b1l = *reinterpret_cast<const short8*>(&Bl[g * 2 + 0][ct * 16 + lr][lk]);
        short8 b2h = *reinterpret_cast<const short8*>(&Bh[g * 2 + 1][ct * 16 + lr][lk]);
        short8 b2l = *reinterpret_cast<const short8*>(&Bl[g * 2 + 1][ct * 16 + lr][lk]);
        ai[g][ct][0] = __builtin_amdgcn_mfma_f32_16x16x32_bf16(agh0, b1h, ai[g][ct][0], 0, 0, 0);
        ai[g][ct][0] = __builtin_amdgcn_mfma_f32_16x16x32_bf16(agh0, b1l, ai[g][ct][0], 0, 0, 0);
        ai[g][ct][0] = __builtin_amdgcn_mfma_f32_16x16x32_bf16(agl0, b1h, ai[g][ct][0], 0, 0, 0);
        ai[g][ct][1] = __builtin_amdgcn_mfma_f32_16x16x32_bf16(agh1, b1h, ai[g][ct][1], 0, 0, 0);
        ai[g][ct][1] = __builtin_amdgcn_mfma_f32_16x16x32_bf16(agh1, b1l, ai[g][ct][1], 0, 0, 0);
        ai[g][ct][1] = __builtin_amdgcn_mfma_f32_16x16x32_bf16(agl1, b1h, ai[g][ct][1], 0, 0, 0);
        ah[g][ct][0] = __builtin_amdgcn_mfma_f32_16x16x32_bf16(hh0, b2h, ah[g][ct][0], 0, 0, 0);
        ah[g][ct][0] = __builtin_amdgcn_mfma_f32_16x16x32_bf16(hh0, b2l, ah[g][ct][0], 0, 0, 0);
        ah[g][ct][0] = __builtin_amdgcn_mfma_f32_16x16x32_bf16(hl0, b2h, ah[g][ct][0], 0, 0, 0);
        ah[g][ct][1] = __builtin_amdgcn_mfma_f32_16x16x32_bf16(hh1, b2h, ah[g][ct][1], 0, 0, 0);
        ah[g][ct][1] = __builtin_amdgcn_mfma_f32_16x16x32_bf16(hh1, b2l, ah[g][ct][1], 0, 0, 0);
        ah[g][ct][1] = __builtin_amdgcn_mfma_f32_16x16x32_bf16(hl1, b2h, ah[g][ct][1], 0, 0, 0);
      }
    }
    __syncthreads();
  }

  // ---- epilogue: GRU gates, write packed hnext ----
#pragma unroll
  for (int ct = 0; ct < 2; ++ct) {
    int c = cc0 + ct * 16 + lr;
    if (c >= DIM) continue;
    float bir = b_ih[c], biz = b_ih[DIM + c], bin = b_ih[2 * DIM + c];
    float bhr = b_hh[c], bhz = b_hh[DIM + c], bhn = b_hh[2 * DIM + c];
#pragma unroll
    for (int rf = 0; rf < 2; ++rf) {
#pragma unroll
      for (int qq = 0; qq < 4; ++qq) {
        int rr_ = row0 + wv * 32 + rf * 16 + (lane >> 4) * 4 + qq;
        if (rr_ >= NN) continue;
        float gir = ai[0][ct][rf][qq] + bir;
        float giz = ai[1][ct][rf][qq] + biz;
        float gin = ai[2][ct][rf][qq] + bin;
        float ghr = ah[0][ct][rf][qq] + bhr;
        float ghz = ah[1][ct][rf][qq] + bhz;
        float ghn = ah[2][ct][rf][qq] + bhn;
        float rr = 1.f / (1.f + __expf(-(gir + ghr)));
        float zz = 1.f / (1.f + __expf(-(giz + ghz)));
        float nn = tanhf(gin + rr * ghn);
        float hv = up_f(hpk[(size_t)rr_ * DIM + c]);
        hnextpk[(size_t)rr_ * DIM + c] = packf((1.f - zz) * nn + zz * hv);
      }
    }
  }
}

// ---------------- relu + segment_max pooling (packed h) ----------------
__global__ __launch_bounds__(256) void k_pool(const uint* __restrict__ hpk,
                                              const int* __restrict__ batch,
                                              float* __restrict__ pooled) {
  int i = blockIdx.x;
  int j = threadIdx.x;
  if (j < DIM) {
    int g = batch[i];
    float v = up_f(hpk[(size_t)i * DIM + j]);
    v = v > 0.f ? v : 0.f;
    atomicMax((int*)&pooled[(size_t)g * DIM + j], __float_as_int(v));
  }
}

__global__ __launch_bounds__(256) void k_classify(const float* __restrict__ pooled,
                                                  const float* __restrict__ w,
                                                  const float* __restrict__ b,
                                                  float* __restrict__ out) {
  __shared__ float r0[256], r1[256];
  int g = blockIdx.x;
  int j = threadIdx.x;
  float p = (j < DIM) ? pooled[(size_t)g * DIM + j] : 0.f;
  r0[j] = (j < DIM) ? p * w[j] : 0.f;
  r1[j] = (j < DIM) ? p * w[DIM + j] : 0.f;
  __syncthreads();
  for (int d = 128; d > 0; d >>= 1) {
    if (j < d) { r0[j] += r0[j + d]; r1[j] += r1[j + d]; }
    __syncthreads();
  }
  if (j == 0) {
    out[g * 2 + 0] = 1.f / (1.f + expf(-(r0[0] + b[0])));
    out[g * 2 + 1] = 1.f / (1.f + expf(-(r1[0] + b[1])));
  }
}

// ---------------- host ----------------
extern "C" void kernel_launch(void* const* d_in, const int* in_sizes, int n_in,
                              void* d_out, int out_size, void* d_ws, size_t ws_size,
                              hipStream_t stream) {
  const float* x = (const float*)d_in[0];
  const int* edge_index = (const int*)d_in[1];
  const int* batch = (const int*)d_in[2];
  const float* ggnn_w = (const float*)d_in[3];
  const float* w_ih = (const float*)d_in[4];
  const float* w_hh = (const float*)d_in[5];
  const float* b_ih = (const float*)d_in[6];
  const float* b_hh = (const float*)d_in[7];
  const float* cls_w = (const float*)d_in[8];
  const float* cls_b = (const float*)d_in[9];
  float* out = (float*)d_out;

  const int* src = edge_index;       // edge_index[0]
  const int* dst = edge_index + NE;  // edge_index[1]

  char* wsb = (char*)d_ws;
  size_t off = 0;
  auto alloc = [&](size_t bytes) -> void* {
    void* p = wsb + off;
    off += (bytes + 255) & ~(size_t)255;
    return p;
  };
  uint* hpkA = (uint*)alloc((size_t)NN * DIM * 4);   // 40 MB
  uint* hpkB = (uint*)alloc((size_t)NN * DIM * 4);   // 40 MB
  uint* aggpk = (uint*)alloc((size_t)NN * DIM * 4);  // 40 MB
  float* Wc_tmp = (float*)alloc((size_t)DIM * 3 * DIM * 4);
  uint* wcT = (uint*)alloc((size_t)NSTEPS * 3 * DIM * DIM * 4);
  uint* whT = (uint*)alloc((size_t)3 * DIM * DIM * 4);
  float* pooled = (float*)alloc((size_t)NG * DIM * 4);
  int* indeg = (int*)alloc((size_t)NN * 4);
  int* offs = (int*)alloc((size_t)(NN + 1) * 4);
  int* slist = (int*)alloc((size_t)NE * 4);
  if (off > ws_size) return;  // fail loud (absmax) instead of faulting

  // h0 = pack(x)
  k_pack_f32<<<2048, 256, 0, stream>>>((const float4*)x, (uint4*)hpkA, NN * DIM / 4);

  // CSR build (dst -> src list)
  k_zero_i32<<<196, 256, 0, stream>>>(indeg, NN);
  k_hist<<<(NE + 255) / 256, 256, 0, stream>>>(dst, indeg, NE);
  k_scan<<<1, 1024, 0, stream>>>(indeg, offs, NN);
  k_copy_i32<<<196, 256, 0, stream>>>(offs, indeg, NN);
  k_scatter<<<(NE + 255) / 256, 256, 0, stream>>>(dst, src, indeg, slist, NE);

  // weights: Wc[s] = ggnn_w[s] @ w_ih^T -> transpose+pack; whT = pack(w_hh)
  {
    dim3 g((3 * DIM + GBN - 1) / GBN, (DIM + GBM - 1) / GBM);
    for (int s = 0; s < NSTEPS; ++s) {
      k_gemm_bt<<<g, 256, 0, stream>>>(ggnn_w + (size_t)s * DIM * DIM, w_ih, Wc_tmp,
                                       DIM, 3 * DIM, DIM);
      k_pack_wcT<<<(600 * DIM + 255) / 256, 256, 0, stream>>>(
          Wc_tmp, wcT + (size_t)s * 3 * DIM * DIM);
    }
    k_pack_f32<<<512, 256, 0, stream>>>((const float4*)w_hh, (uint4*)whT, 3 * DIM * DIM / 4);
  }

  uint* hcur = hpkA;
  uint* hnext = hpkB;
  for (int s = 0; s < NSTEPS; ++s) {
    k_aggregate_pk<<<(NN + 3) / 4, 256, 0, stream>>>(hcur, offs, slist, aggpk);
    k_fused_mfma<<<NRB * NCB, 256, 0, stream>>>(aggpk, hcur,
                                                wcT + (size_t)s * 3 * DIM * DIM,
                                                whT, b_ih, b_hh, hnext);
    uint* t = hcur; hcur = hnext; hnext = t;
  }

  k_zero_f32<<<200, 256, 0, stream>>>(pooled, NG * DIM);
  k_pool<<<NN, 256, 0, stream>>>(hcur, batch, pooled);
  k_classify<<<NG, 256, 0, stream>>>(pooled, cls_w, cls_b, out);
}

// Round 5
// 1719.786 us; speedup vs baseline: 2.8559x; 1.1037x over previous
//
#include <hip/hip_runtime.h>
#include <cstdint>
#include <cstddef>

#define NN 50000
#define NE 400000
#define NG 256
#define DIM 200
#define NSTEPS 6

typedef unsigned int uint;
typedef unsigned short ushort;
typedef __attribute__((ext_vector_type(8))) short short8;
typedef __attribute__((ext_vector_type(4))) short short4v;
typedef __attribute__((ext_vector_type(4))) float f32x4;

// ---- packed split-bf16 helpers: word = (hi_bf16 << 16) | lo_bf16 ----
__device__ __forceinline__ float up_hi(uint w) { return __uint_as_float(w & 0xffff0000u); }
__device__ __forceinline__ float up_lo(uint w) { return __uint_as_float(w << 16); }
__device__ __forceinline__ float up_f(uint w) { return up_hi(w) + up_lo(w); }
__device__ __forceinline__ uint packf(float v) {
  uint u = __float_as_uint(v);
  uint t = u + 0x7fffu + ((u >> 16) & 1u);   // RN-even to bf16
  uint hb = t & 0xffff0000u;
  float lo = v - __uint_as_float(hb);
  uint ul = __float_as_uint(lo);
  uint t2 = ul + 0x7fffu + ((ul >> 16) & 1u);
  return hb | (t2 >> 16);
}
__device__ __forceinline__ ushort bf16rn(float v) {
  uint u = __float_as_uint(v);
  return (ushort)((u + 0x7fffu + ((u >> 16) & 1u)) >> 16);
}

// ---------------- utility kernels ----------------
__global__ void k_zero_i32(int* __restrict__ p, int n) {
  for (int i = blockIdx.x * blockDim.x + threadIdx.x; i < n; i += gridDim.x * blockDim.x)
    p[i] = 0;
}
__global__ void k_zero_f32(float* __restrict__ p, int n) {
  for (int i = blockIdx.x * blockDim.x + threadIdx.x; i < n; i += gridDim.x * blockDim.x)
    p[i] = 0.f;
}
__global__ void k_copy_i32(const int* __restrict__ a, int* __restrict__ b, int n) {
  for (int i = blockIdx.x * blockDim.x + threadIdx.x; i < n; i += gridDim.x * blockDim.x)
    b[i] = a[i];
}
__global__ void k_hist(const int* __restrict__ dst, int* __restrict__ cnt, int nE) {
  int e = blockIdx.x * blockDim.x + threadIdx.x;
  if (e < nE) atomicAdd(&cnt[dst[e]], 1);
}
__global__ void k_scan(const int* __restrict__ cnt, int* __restrict__ off, int n) {
  __shared__ int buf[1024];
  __shared__ int carry;
  int tid = threadIdx.x;
  if (tid == 0) { carry = 0; off[0] = 0; }
  __syncthreads();
  for (int base = 0; base < n; base += 1024) {
    int i = base + tid;
    int v = (i < n) ? cnt[i] : 0;
    buf[tid] = v;
    __syncthreads();
    for (int d = 1; d < 1024; d <<= 1) {
      int t = (tid >= d) ? buf[tid - d] : 0;
      __syncthreads();
      buf[tid] += t;
      __syncthreads();
    }
    if (i < n) off[i + 1] = carry + buf[tid];
    __syncthreads();
    if (tid == 0) carry += buf[1023];
    __syncthreads();
  }
}
__global__ void k_scatter(const int* __restrict__ dst, const int* __restrict__ src,
                          int* __restrict__ cursor, int* __restrict__ slist, int nE) {
  int e = blockIdx.x * blockDim.x + threadIdx.x;
  if (e < nE) {
    int d = dst[e];
    int pos = atomicAdd(&cursor[d], 1);
    slist[pos] = src[e];
  }
}

// pack fp32 array -> packed split-bf16 (vectorized)
__global__ void k_pack_f32(const float4* __restrict__ in, uint4* __restrict__ out, int n4) {
  for (int i = blockIdx.x * blockDim.x + threadIdx.x; i < n4; i += gridDim.x * blockDim.x) {
    float4 v = in[i];
    uint4 o;
    o.x = packf(v.x); o.y = packf(v.y); o.z = packf(v.z); o.w = packf(v.w);
    out[i] = o;
  }
}

// elementwise fp32 -> bf16 ushort
__global__ void k_pack_bf(const float* __restrict__ in, ushort* __restrict__ out, int n) {
  for (int i = blockIdx.x * blockDim.x + threadIdx.x; i < n; i += gridDim.x * blockDim.x)
    out[i] = bf16rn(in[i]);
}

// transpose+pack: Wc fp32 [200][600] -> bf16 ushort [600][200]
__global__ void k_pack_wcT(const float* __restrict__ Wc, ushort* __restrict__ out) {
  int idx = blockIdx.x * blockDim.x + threadIdx.x;
  if (idx < 600 * DIM) {
    int c = idx / DIM, k = idx - c * DIM;
    out[idx] = bf16rn(Wc[(size_t)k * 600 + c]);
  }
}

// ---------------- fp32 GEMM (tiny, for Wc = W @ w_ih^T) ----------------
#define GBM 64
#define GBN 64
#define GBK 8
__global__ __launch_bounds__(256) void k_gemm_bt(const float* __restrict__ A,
                                                 const float* __restrict__ B,
                                                 float* __restrict__ C,
                                                 int M, int N, int K) {
  __shared__ __align__(16) float As[GBK][GBM];
  __shared__ __align__(16) float Bs[GBK][GBN];
  int tid = threadIdx.x;
  int row0 = blockIdx.y * GBM;
  int col0 = blockIdx.x * GBN;
  int ty = tid >> 4, tx = tid & 15;
  float acc[4][4] = {};
  for (int k0 = 0; k0 < K; k0 += GBK) {
    {
      int r = tid >> 2;
      int kk = (tid & 3) * 2;
      int gr = row0 + r;
      float2 v = make_float2(0.f, 0.f);
      if (gr < M) v = *reinterpret_cast<const float2*>(&A[(size_t)gr * K + k0 + kk]);
      As[kk][r] = v.x; As[kk + 1][r] = v.y;
    }
    {
      int n = tid >> 2;
      int kk = (tid & 3) * 2;
      int gn = col0 + n;
      float2 v = make_float2(0.f, 0.f);
      if (gn < N) v = *reinterpret_cast<const float2*>(&B[(size_t)gn * K + k0 + kk]);
      Bs[kk][n] = v.x; Bs[kk + 1][n] = v.y;
    }
    __syncthreads();
#pragma unroll
    for (int k = 0; k < GBK; ++k) {
      float4 av = *reinterpret_cast<const float4*>(&As[k][ty * 4]);
      float4 bv = *reinterpret_cast<const float4*>(&Bs[k][tx * 4]);
      float a[4] = {av.x, av.y, av.z, av.w};
      float b[4] = {bv.x, bv.y, bv.z, bv.w};
#pragma unroll
      for (int i = 0; i < 4; ++i)
#pragma unroll
        for (int j = 0; j < 4; ++j) acc[i][j] += a[i] * b[j];
    }
    __syncthreads();
  }
#pragma unroll
  for (int i = 0; i < 4; ++i) {
    int r = row0 + ty * 4 + i;
    if (r >= M) continue;
#pragma unroll
    for (int j = 0; j < 4; ++j) {
      int c = col0 + tx * 4 + j;
      if (c < N) C[(size_t)r * N + c] = acc[i][j];
    }
  }
}

// ---------------- aggregation: wave per node, uint4 per lane ----------------
__global__ __launch_bounds__(256) void k_aggregate_pk(const uint* __restrict__ hpk,
                                                      const int* __restrict__ off,
                                                      const int* __restrict__ slist,
                                                      uint* __restrict__ aggpk) {
  int node = blockIdx.x * 4 + (threadIdx.x >> 6);
  if (node >= NN) return;
  int lane = threadIdx.x & 63;
  int c4 = lane * 4;
  bool act = c4 < DIM;
  float a0 = 0.f, a1 = 0.f, a2 = 0.f, a3 = 0.f;
  int beg = off[node], end = off[node + 1];
  int p = beg;
  for (; p + 1 < end; p += 2) {
    int s0 = slist[p];
    int s1 = slist[p + 1];
    if (act) {
      uint4 u0 = *reinterpret_cast<const uint4*>(hpk + (size_t)s0 * DIM + c4);
      uint4 u1 = *reinterpret_cast<const uint4*>(hpk + (size_t)s1 * DIM + c4);
      a0 += up_f(u0.x) + up_f(u1.x);
      a1 += up_f(u0.y) + up_f(u1.y);
      a2 += up_f(u0.z) + up_f(u1.z);
      a3 += up_f(u0.w) + up_f(u1.w);
    }
  }
  if (p < end) {
    int s = slist[p];
    if (act) {
      uint4 u = *reinterpret_cast<const uint4*>(hpk + (size_t)s * DIM + c4);
      a0 += up_f(u.x); a1 += up_f(u.y); a2 += up_f(u.z); a3 += up_f(u.w);
    }
  }
  if (act) {
    uint4 o;
    o.x = packf(a0); o.y = packf(a1); o.z = packf(a2); o.w = packf(a3);
    *reinterpret_cast<uint4*>(aggpk + (size_t)node * DIM + c4) = o;
  }
}

// ---------------- fused MFMA GRU step ----------------
// Block: 128 rows x 32 cols, 4 waves. A split hi/lo (exact), B plain bf16.
// Register-staged prefetch: ktile t+1 global loads issued before compute of t.
#define KT 32
#define NKT 7
#define NRB ((NN + 127) / 128)   // 391
#define NCB 7

__global__ __launch_bounds__(256, 2) void k_fused_mfma(
    const uint* __restrict__ aggpk, const uint* __restrict__ hpk,
    const ushort* __restrict__ wcB, const ushort* __restrict__ whB,
    const float* __restrict__ b_ih, const float* __restrict__ b_hh,
    uint* __restrict__ hnextpk) {
  __shared__ short Ah[2][128][40];   // [mat 0=agg,1=h][row][k] hi (stride 80B)
  __shared__ short Al[2][128][40];   // lo
  __shared__ short Bh[6][32][40];    // [gate*2 + (0=Wc,1=whT)][col][k] bf16

  int tid = threadIdx.x;
  int lane = tid & 63;
  int wv = tid >> 6;

  // XCD-aware bijective swizzle (m204)
  int nwg = NRB * NCB;            // 2737
  int q = nwg >> 3, r = nwg & 7;
  int x = blockIdx.x & 7, ii = blockIdx.x >> 3;
  int work = (x < r ? x * (q + 1) : r * (q + 1) + (x - r) * q) + ii;
  int rb = work / NCB;
  int cb = work - rb * NCB;
  int row0 = rb * 128;
  int cc0 = cb * 32;

  f32x4 ai[3][2][2] = {};   // [gate][ct][rf]
  f32x4 ah[3][2][2] = {};

  int lr = lane & 15;
  int lk = (lane >> 4) * 8;

  uint4 areg[8];
  short4v breg[6];

  // decomposed ids (constant per thread)
  int a_mat[8], a_row[8], a_k[8];
#pragma unroll
  for (int rep = 0; rep < 8; ++rep) {
    int id = tid + rep * 256;
    a_mat[rep] = id >> 10;
    int rem = id & 1023;
    a_row[rep] = rem >> 3;
    a_k[rep] = (rem & 7) * 4;
  }
  int b_mat[6], b_col[6], b_k[6];
#pragma unroll
  for (int rep = 0; rep < 6; ++rep) {
    int id = tid + rep * 256;
    b_mat[rep] = id >> 8;
    int rem = id & 255;
    b_col[rep] = rem >> 3;
    b_k[rep] = (rem & 7) * 4;
  }

  auto loadA = [&](int t) {
    int kt = t * KT;
#pragma unroll
    for (int rep = 0; rep < 8; ++rep) {
      int gr = row0 + a_row[rep];
      int gk = kt + a_k[rep];
      bool valid = (gr < NN) && (gk < DIM);
      const uint* sp = (a_mat[rep] ? hpk : aggpk) + (size_t)gr * DIM + gk;
      areg[rep] = valid ? *reinterpret_cast<const uint4*>(sp) : make_uint4(0, 0, 0, 0);
    }
  };
  auto loadB = [&](int t) {
    int kt = t * KT;
#pragma unroll
    for (int rep = 0; rep < 6; ++rep) {
      int g = b_mat[rep] >> 1;
      int which = b_mat[rep] & 1;
      int gcol = g * DIM + cc0 + b_col[rep];
      int gk = kt + b_k[rep];
      bool valid = (cc0 + b_col[rep] < DIM) && (gk < DIM);
      const ushort* sp = (which ? whB : wcB) + (size_t)gcol * DIM + gk;
      breg[rep] = valid ? *reinterpret_cast<const short4v*>(sp) : (short4v){0, 0, 0, 0};
    }
  };
  auto storeAB = [&]() {
#pragma unroll
    for (int rep = 0; rep < 8; ++rep) {
      uint4 u = areg[rep];
      short4v hs = {(short)(u.x >> 16), (short)(u.y >> 16), (short)(u.z >> 16), (short)(u.w >> 16)};
      short4v ls = {(short)(u.x & 0xffff), (short)(u.y & 0xffff), (short)(u.z & 0xffff), (short)(u.w & 0xffff)};
      *reinterpret_cast<short4v*>(&Ah[a_mat[rep]][a_row[rep]][a_k[rep]]) = hs;
      *reinterpret_cast<short4v*>(&Al[a_mat[rep]][a_row[rep]][a_k[rep]]) = ls;
    }
#pragma unroll
    for (int rep = 0; rep < 6; ++rep)
      *reinterpret_cast<short4v*>(&Bh[b_mat[rep]][b_col[rep]][b_k[rep]]) = breg[rep];
  };

  loadA(0);
  loadB(0);
  storeAB();

  for (int t = 0; t < NKT; ++t) {
    __syncthreads();
    if (t + 1 < NKT) { loadA(t + 1); loadB(t + 1); }  // prefetch next ktile

    short8 agh0 = *reinterpret_cast<const short8*>(&Ah[0][wv * 32 + lr][lk]);
    short8 agh1 = *reinterpret_cast<const short8*>(&Ah[0][wv * 32 + 16 + lr][lk]);
    short8 agl0 = *reinterpret_cast<const short8*>(&Al[0][wv * 32 + lr][lk]);
    short8 agl1 = *reinterpret_cast<const short8*>(&Al[0][wv * 32 + 16 + lr][lk]);
    short8 hh0 = *reinterpret_cast<const short8*>(&Ah[1][wv * 32 + lr][lk]);
    short8 hh1 = *reinterpret_cast<const short8*>(&Ah[1][wv * 32 + 16 + lr][lk]);
    short8 hl0 = *reinterpret_cast<const short8*>(&Al[1][wv * 32 + lr][lk]);
    short8 hl1 = *reinterpret_cast<const short8*>(&Al[1][wv * 32 + 16 + lr][lk]);
#pragma unroll
    for (int g = 0; g < 3; ++g) {
#pragma unroll
      for (int ct = 0; ct < 2; ++ct) {
        short8 b1h = *reinterpret_cast<const short8*>(&Bh[g * 2 + 0][ct * 16 + lr][lk]);
        short8 b2h = *reinterpret_cast<const short8*>(&Bh[g * 2 + 1][ct * 16 + lr][lk]);
        ai[g][ct][0] = __builtin_amdgcn_mfma_f32_16x16x32_bf16(agh0, b1h, ai[g][ct][0], 0, 0, 0);
        ai[g][ct][0] = __builtin_amdgcn_mfma_f32_16x16x32_bf16(agl0, b1h, ai[g][ct][0], 0, 0, 0);
        ai[g][ct][1] = __builtin_amdgcn_mfma_f32_16x16x32_bf16(agh1, b1h, ai[g][ct][1], 0, 0, 0);
        ai[g][ct][1] = __builtin_amdgcn_mfma_f32_16x16x32_bf16(agl1, b1h, ai[g][ct][1], 0, 0, 0);
        ah[g][ct][0] = __builtin_amdgcn_mfma_f32_16x16x32_bf16(hh0, b2h, ah[g][ct][0], 0, 0, 0);
        ah[g][ct][0] = __builtin_amdgcn_mfma_f32_16x16x32_bf16(hl0, b2h, ah[g][ct][0], 0, 0, 0);
        ah[g][ct][1] = __builtin_amdgcn_mfma_f32_16x16x32_bf16(hh1, b2h, ah[g][ct][1], 0, 0, 0);
        ah[g][ct][1] = __builtin_amdgcn_mfma_f32_16x16x32_bf16(hl1, b2h, ah[g][ct][1], 0, 0, 0);
      }
    }
    __syncthreads();
    if (t + 1 < NKT) storeAB();
  }

  // ---- epilogue: GRU gates, write packed hnext ----
#pragma unroll
  for (int ct = 0; ct < 2; ++ct) {
    int c = cc0 + ct * 16 + lr;
    if (c >= DIM) continue;
    float bir = b_ih[c], biz = b_ih[DIM + c], bin = b_ih[2 * DIM + c];
    float bhr = b_hh[c], bhz = b_hh[DIM + c], bhn = b_hh[2 * DIM + c];
#pragma unroll
    for (int rf = 0; rf < 2; ++rf) {
#pragma unroll
      for (int qq = 0; qq < 4; ++qq) {
        int rr_ = row0 + wv * 32 + rf * 16 + (lane >> 4) * 4 + qq;
        if (rr_ >= NN) continue;
        float gir = ai[0][ct][rf][qq] + bir;
        float giz = ai[1][ct][rf][qq] + biz;
        float gin = ai[2][ct][rf][qq] + bin;
        float ghr = ah[0][ct][rf][qq] + bhr;
        float ghz = ah[1][ct][rf][qq] + bhz;
        float ghn = ah[2][ct][rf][qq] + bhn;
        float rr = 1.f / (1.f + __expf(-(gir + ghr)));
        float zz = 1.f / (1.f + __expf(-(giz + ghz)));
        float nn = tanhf(gin + rr * ghn);
        float hv = up_f(hpk[(size_t)rr_ * DIM + c]);
        hnextpk[(size_t)rr_ * DIM + c] = packf((1.f - zz) * nn + zz * hv);
      }
    }
  }
}

// ---------------- relu + segment_max pooling (packed h) ----------------
__global__ __launch_bounds__(256) void k_pool(const uint* __restrict__ hpk,
                                              const int* __restrict__ batch,
                                              float* __restrict__ pooled) {
  int i = blockIdx.x;
  int j = threadIdx.x;
  if (j < DIM) {
    int g = batch[i];
    float v = up_f(hpk[(size_t)i * DIM + j]);
    v = v > 0.f ? v : 0.f;
    atomicMax((int*)&pooled[(size_t)g * DIM + j], __float_as_int(v));
  }
}

__global__ __launch_bounds__(256) void k_classify(const float* __restrict__ pooled,
                                                  const float* __restrict__ w,
                                                  const float* __restrict__ b,
                                                  float* __restrict__ out) {
  __shared__ float r0[256], r1[256];
  int g = blockIdx.x;
  int j = threadIdx.x;
  float p = (j < DIM) ? pooled[(size_t)g * DIM + j] : 0.f;
  r0[j] = (j < DIM) ? p * w[j] : 0.f;
  r1[j] = (j < DIM) ? p * w[DIM + j] : 0.f;
  __syncthreads();
  for (int d = 128; d > 0; d >>= 1) {
    if (j < d) { r0[j] += r0[j + d]; r1[j] += r1[j + d]; }
    __syncthreads();
  }
  if (j == 0) {
    out[g * 2 + 0] = 1.f / (1.f + expf(-(r0[0] + b[0])));
    out[g * 2 + 1] = 1.f / (1.f + expf(-(r1[0] + b[1])));
  }
}

// ---------------- host ----------------
extern "C" void kernel_launch(void* const* d_in, const int* in_sizes, int n_in,
                              void* d_out, int out_size, void* d_ws, size_t ws_size,
                              hipStream_t stream) {
  const float* x = (const float*)d_in[0];
  const int* edge_index = (const int*)d_in[1];
  const int* batch = (const int*)d_in[2];
  const float* ggnn_w = (const float*)d_in[3];
  const float* w_ih = (const float*)d_in[4];
  const float* w_hh = (const float*)d_in[5];
  const float* b_ih = (const float*)d_in[6];
  const float* b_hh = (const float*)d_in[7];
  const float* cls_w = (const float*)d_in[8];
  const float* cls_b = (const float*)d_in[9];
  float* out = (float*)d_out;

  const int* src = edge_index;       // edge_index[0]
  const int* dst = edge_index + NE;  // edge_index[1]

  char* wsb = (char*)d_ws;
  size_t off = 0;
  auto alloc = [&](size_t bytes) -> void* {
    void* p = wsb + off;
    off += (bytes + 255) & ~(size_t)255;
    return p;
  };
  uint* hpkA = (uint*)alloc((size_t)NN * DIM * 4);   // 40 MB
  uint* hpkB = (uint*)alloc((size_t)NN * DIM * 4);   // 40 MB
  uint* aggpk = (uint*)alloc((size_t)NN * DIM * 4);  // 40 MB
  float* Wc_tmp = (float*)alloc((size_t)DIM * 3 * DIM * 4);
  ushort* wcB = (ushort*)alloc((size_t)NSTEPS * 3 * DIM * DIM * 2);  // 1.44 MB
  ushort* whB = (ushort*)alloc((size_t)3 * DIM * DIM * 2);           // 240 KB
  float* pooled = (float*)alloc((size_t)NG * DIM * 4);
  int* indeg = (int*)alloc((size_t)NN * 4);
  int* offs = (int*)alloc((size_t)(NN + 1) * 4);
  int* slist = (int*)alloc((size_t)NE * 4);
  if (off > ws_size) return;  // fail loud (absmax) instead of faulting

  // h0 = pack(x)
  k_pack_f32<<<2048, 256, 0, stream>>>((const float4*)x, (uint4*)hpkA, NN * DIM / 4);

  // CSR build (dst -> src list)
  k_zero_i32<<<196, 256, 0, stream>>>(indeg, NN);
  k_hist<<<(NE + 255) / 256, 256, 0, stream>>>(dst, indeg, NE);
  k_scan<<<1, 1024, 0, stream>>>(indeg, offs, NN);
  k_copy_i32<<<196, 256, 0, stream>>>(offs, indeg, NN);
  k_scatter<<<(NE + 255) / 256, 256, 0, stream>>>(dst, src, indeg, slist, NE);

  // weights: Wc[s] = ggnn_w[s] @ w_ih^T -> transpose to bf16 [600][200]; whB = bf16(w_hh)
  {
    dim3 g((3 * DIM + GBN - 1) / GBN, (DIM + GBM - 1) / GBM);
    for (int s = 0; s < NSTEPS; ++s) {
      k_gemm_bt<<<g, 256, 0, stream>>>(ggnn_w + (size_t)s * DIM * DIM, w_ih, Wc_tmp,
                                       DIM, 3 * DIM, DIM);
      k_pack_wcT<<<(600 * DIM + 255) / 256, 256, 0, stream>>>(
          Wc_tmp, wcB + (size_t)s * 3 * DIM * DIM);
    }
    k_pack_bf<<<512, 256, 0, stream>>>(w_hh, whB, 3 * DIM * DIM);
  }

  uint* hcur = hpkA;
  uint* hnext = hpkB;
  for (int s = 0; s < NSTEPS; ++s) {
    k_aggregate_pk<<<(NN + 3) / 4, 256, 0, stream>>>(hcur, offs, slist, aggpk);
    k_fused_mfma<<<NRB * NCB, 256, 0, stream>>>(aggpk, hcur,
                                                wcB + (size_t)s * 3 * DIM * DIM,
                                                whB, b_ih, b_hh, hnext);
    uint* t = hcur; hcur = hnext; hnext = t;
  }

  k_zero_f32<<<200, 256, 0, stream>>>(pooled, NG * DIM);
  k_pool<<<NN, 256, 0, stream>>>(hcur, batch, pooled);
  k_classify<<<NG, 256, 0, stream>>>(pooled, cls_w, cls_b, out);
}

// Round 6
// 1640.416 us; speedup vs baseline: 2.9940x; 1.0484x over previous
//
#include <hip/hip_runtime.h>
#include <cstdint>
#include <cstddef>

#define NN 50000
#define NE 400000
#define NG 256
#define DIM 200
#define NSTEPS 6

typedef unsigned int uint;
typedef unsigned short ushort;
typedef __attribute__((ext_vector_type(8))) short short8;
typedef __attribute__((ext_vector_type(4))) float f32x4;

#define GLL16(gsrc, ldst)                                                        \
  __builtin_amdgcn_global_load_lds(                                              \
      (const __attribute__((address_space(1))) void*)(gsrc),                     \
      (__attribute__((address_space(3))) void*)(ldst), 16, 0, 0)

// ---- packed split-bf16 helpers: word = (hi_bf16 << 16) | lo_bf16 ----
__device__ __forceinline__ float up_hi(uint w) { return __uint_as_float(w & 0xffff0000u); }
__device__ __forceinline__ float up_lo(uint w) { return __uint_as_float(w << 16); }
__device__ __forceinline__ float up_f(uint w) { return up_hi(w) + up_lo(w); }
__device__ __forceinline__ uint packf(float v) {
  uint u = __float_as_uint(v);
  uint t = u + 0x7fffu + ((u >> 16) & 1u);   // RN-even to bf16
  uint hb = t & 0xffff0000u;
  float lo = v - __uint_as_float(hb);
  uint ul = __float_as_uint(lo);
  uint t2 = ul + 0x7fffu + ((ul >> 16) & 1u);
  return hb | (t2 >> 16);
}
__device__ __forceinline__ ushort bf16rn(float v) {
  uint u = __float_as_uint(v);
  return (ushort)((u + 0x7fffu + ((u >> 16) & 1u)) >> 16);
}

// ---------------- utility kernels ----------------
__global__ void k_zero_i32(int* __restrict__ p, int n) {
  for (int i = blockIdx.x * blockDim.x + threadIdx.x; i < n; i += gridDim.x * blockDim.x)
    p[i] = 0;
}
__global__ void k_zero_f32(float* __restrict__ p, int n) {
  for (int i = blockIdx.x * blockDim.x + threadIdx.x; i < n; i += gridDim.x * blockDim.x)
    p[i] = 0.f;
}
__global__ void k_copy_i32(const int* __restrict__ a, int* __restrict__ b, int n) {
  for (int i = blockIdx.x * blockDim.x + threadIdx.x; i < n; i += gridDim.x * blockDim.x)
    b[i] = a[i];
}
__global__ void k_hist(const int* __restrict__ dst, int* __restrict__ cnt, int nE) {
  int e = blockIdx.x * blockDim.x + threadIdx.x;
  if (e < nE) atomicAdd(&cnt[dst[e]], 1);
}
__global__ void k_scan(const int* __restrict__ cnt, int* __restrict__ off, int n) {
  __shared__ int buf[1024];
  __shared__ int carry;
  int tid = threadIdx.x;
  if (tid == 0) { carry = 0; off[0] = 0; }
  __syncthreads();
  for (int base = 0; base < n; base += 1024) {
    int i = base + tid;
    int v = (i < n) ? cnt[i] : 0;
    buf[tid] = v;
    __syncthreads();
    for (int d = 1; d < 1024; d <<= 1) {
      int t = (tid >= d) ? buf[tid - d] : 0;
      __syncthreads();
      buf[tid] += t;
      __syncthreads();
    }
    if (i < n) off[i + 1] = carry + buf[tid];
    __syncthreads();
    if (tid == 0) carry += buf[1023];
    __syncthreads();
  }
}
__global__ void k_scatter(const int* __restrict__ dst, const int* __restrict__ src,
                          int* __restrict__ cursor, int* __restrict__ slist, int nE) {
  int e = blockIdx.x * blockDim.x + threadIdx.x;
  if (e < nE) {
    int d = dst[e];
    int pos = atomicAdd(&cursor[d], 1);
    slist[pos] = src[e];
  }
}

// pack fp32 array -> packed split-bf16 (vectorized)
__global__ void k_pack_f32(const float4* __restrict__ in, uint4* __restrict__ out, int n4) {
  for (int i = blockIdx.x * blockDim.x + threadIdx.x; i < n4; i += gridDim.x * blockDim.x) {
    float4 v = in[i];
    uint4 o;
    o.x = packf(v.x); o.y = packf(v.y); o.z = packf(v.z); o.w = packf(v.w);
    out[i] = o;
  }
}

// elementwise fp32 -> bf16 ushort
__global__ void k_pack_bf(const float* __restrict__ in, ushort* __restrict__ out, int n) {
  for (int i = blockIdx.x * blockDim.x + threadIdx.x; i < n; i += gridDim.x * blockDim.x)
    out[i] = bf16rn(in[i]);
}

// transpose+pack: Wc fp32 [200][600] -> bf16 ushort [600][200]
__global__ void k_pack_wcT(const float* __restrict__ Wc, ushort* __restrict__ out) {
  int idx = blockIdx.x * blockDim.x + threadIdx.x;
  if (idx < 600 * DIM) {
    int c = idx / DIM, k = idx - c * DIM;
    out[idx] = bf16rn(Wc[(size_t)k * 600 + c]);
  }
}

// ---------------- fp32 GEMM (tiny, for Wc = W @ w_ih^T) ----------------
#define GBM 64
#define GBN 64
#define GBK 8
__global__ __launch_bounds__(256) void k_gemm_bt(const float* __restrict__ A,
                                                 const float* __restrict__ B,
                                                 float* __restrict__ C,
                                                 int M, int N, int K) {
  __shared__ __align__(16) float As[GBK][GBM];
  __shared__ __align__(16) float Bs[GBK][GBN];
  int tid = threadIdx.x;
  int row0 = blockIdx.y * GBM;
  int col0 = blockIdx.x * GBN;
  int ty = tid >> 4, tx = tid & 15;
  float acc[4][4] = {};
  for (int k0 = 0; k0 < K; k0 += GBK) {
    {
      int r = tid >> 2;
      int kk = (tid & 3) * 2;
      int gr = row0 + r;
      float2 v = make_float2(0.f, 0.f);
      if (gr < M) v = *reinterpret_cast<const float2*>(&A[(size_t)gr * K + k0 + kk]);
      As[kk][r] = v.x; As[kk + 1][r] = v.y;
    }
    {
      int n = tid >> 2;
      int kk = (tid & 3) * 2;
      int gn = col0 + n;
      float2 v = make_float2(0.f, 0.f);
      if (gn < N) v = *reinterpret_cast<const float2*>(&B[(size_t)gn * K + k0 + kk]);
      Bs[kk][n] = v.x; Bs[kk + 1][n] = v.y;
    }
    __syncthreads();
#pragma unroll
    for (int k = 0; k < GBK; ++k) {
      float4 av = *reinterpret_cast<const float4*>(&As[k][ty * 4]);
      float4 bv = *reinterpret_cast<const float4*>(&Bs[k][tx * 4]);
      float a[4] = {av.x, av.y, av.z, av.w};
      float b[4] = {bv.x, bv.y, bv.z, bv.w};
#pragma unroll
      for (int i = 0; i < 4; ++i)
#pragma unroll
        for (int j = 0; j < 4; ++j) acc[i][j] += a[i] * b[j];
    }
    __syncthreads();
  }
#pragma unroll
  for (int i = 0; i < 4; ++i) {
    int r = row0 + ty * 4 + i;
    if (r >= M) continue;
#pragma unroll
    for (int j = 0; j < 4; ++j) {
      int c = col0 + tx * 4 + j;
      if (c < N) C[(size_t)r * N + c] = acc[i][j];
    }
  }
}

// ---------------- aggregation: wave per node, uint4 per lane ----------------
__global__ __launch_bounds__(256) void k_aggregate_pk(const uint* __restrict__ hpk,
                                                      const int* __restrict__ off,
                                                      const int* __restrict__ slist,
                                                      uint* __restrict__ aggpk) {
  int node = blockIdx.x * 4 + (threadIdx.x >> 6);
  if (node >= NN) return;
  int lane = threadIdx.x & 63;
  int c4 = lane * 4;
  bool act = c4 < DIM;
  float a0 = 0.f, a1 = 0.f, a2 = 0.f, a3 = 0.f;
  int beg = off[node], end = off[node + 1];
  int p = beg;
  for (; p + 1 < end; p += 2) {
    int s0 = slist[p];
    int s1 = slist[p + 1];
    if (act) {
      uint4 u0 = *reinterpret_cast<const uint4*>(hpk + (size_t)s0 * DIM + c4);
      uint4 u1 = *reinterpret_cast<const uint4*>(hpk + (size_t)s1 * DIM + c4);
      a0 += up_f(u0.x) + up_f(u1.x);
      a1 += up_f(u0.y) + up_f(u1.y);
      a2 += up_f(u0.z) + up_f(u1.z);
      a3 += up_f(u0.w) + up_f(u1.w);
    }
  }
  if (p < end) {
    int s = slist[p];
    if (act) {
      uint4 u = *reinterpret_cast<const uint4*>(hpk + (size_t)s * DIM + c4);
      a0 += up_f(u.x); a1 += up_f(u.y); a2 += up_f(u.z); a3 += up_f(u.w);
    }
  }
  if (act) {
    uint4 o;
    o.x = packf(a0); o.y = packf(a1); o.z = packf(a2); o.w = packf(a3);
    *reinterpret_cast<uint4*>(aggpk + (size_t)node * DIM + c4) = o;
  }
}

// ---------------- fused MFMA GRU step (global_load_lds + B-resident) ----------
// Block: 512 thr (8 waves), tile 128 rows x 32 cols, wave = 16 rows.
// A packed uint staged via global_load_lds, dbuf, k-major [mat][chunk][row].
// B (6 gate-mats, 32 cols, 224 k bf16) preloaded ONCE, [mat][chunk][col].
#define KT 32
#define NKT 7
#define NRB ((NN + 127) / 128)   // 391
#define NCB 7
#define NT 512

__device__ __forceinline__ void unpack16(const uint4 p0, const uint4 p1,
                                         short8& hi, short8& lo) {
  union U { uint u[4]; short8 s; };
  U H, L;
  H.u[0] = (p0.x >> 16) | (p0.y & 0xffff0000u);
  H.u[1] = (p0.z >> 16) | (p0.w & 0xffff0000u);
  H.u[2] = (p1.x >> 16) | (p1.y & 0xffff0000u);
  H.u[3] = (p1.z >> 16) | (p1.w & 0xffff0000u);
  L.u[0] = (p0.x & 0xffffu) | (p0.y << 16);
  L.u[1] = (p0.z & 0xffffu) | (p0.w << 16);
  L.u[2] = (p1.x & 0xffffu) | (p1.y << 16);
  L.u[3] = (p1.z & 0xffffu) | (p1.w << 16);
  hi = H.s; lo = L.s;
}

__global__ __launch_bounds__(512, 2) void k_fused_mfma(
    const uint* __restrict__ aggpk, const uint* __restrict__ hpk,
    const ushort* __restrict__ wcB, const ushort* __restrict__ whB,
    const float* __restrict__ b_ih, const float* __restrict__ b_hh,
    uint* __restrict__ hnextpk) {
  __shared__ uint4 Apk[2][2][8][128];  // [buf][mat][chunk4u][row]  64 KB
  __shared__ uint4 Bb[6][28][32];      // [mat][chunk8s][col]       84 KB

  int tid = threadIdx.x;
  int lane = tid & 63;
  int wv = tid >> 6;          // 0..7
  int lr = lane & 15;
  int kc = lane >> 4;         // 0..3

  // XCD-aware bijective swizzle (m204)
  int nwg = NRB * NCB;
  int q = nwg >> 3, r = nwg & 7;
  int x = blockIdx.x & 7, ii = blockIdx.x >> 3;
  int work = (x < r ? x * (q + 1) : r * (q + 1) + (x - r) * q) + ii;
  int rb = work / NCB;
  int cb = work - rb * NCB;
  int row0 = rb * 128;
  int cc0 = cb * 32;

  uint4* ApkF = &Apk[0][0][0][0];
  uint4* BbF = &Bb[0][0][0];

  // ---- A staging constants (4 units of 16B per thread per tile) ----
  const uint* aSrc[4];
  int aUnit[4], aChunk[4];
#pragma unroll
  for (int i = 0; i < 4; ++i) {
    int id = tid + i * NT;        // 0..2047
    int mat = id >> 10;
    int chunk = (id >> 7) & 7;
    int row = id & 127;
    int gr = row0 + row; if (gr >= NN) gr = NN - 1;
    aUnit[i] = id;
    aChunk[i] = chunk;
    aSrc[i] = (mat ? hpk : aggpk) + (size_t)gr * DIM + chunk * 4;
  }

  // ---- prologue: stage B (once) + A tile 0 ----
#pragma unroll
  for (int i = 0; i < 11; ++i) {
    int u = tid + i * NT;
    if (u < 5376) {               // whole-wave uniform at the boundary
      int mat = u / 896;
      int rem = u - mat * 896;
      int chunk = rem >> 5;
      int col = rem & 31;
      int g = mat >> 1;
      const ushort* wsrc = (mat & 1) ? whB : wcB;
      const ushort* sp = wsrc + (size_t)(g * DIM + cc0 + col) * DIM + chunk * 8;
      GLL16(sp, BbF + u);
    }
  }
#pragma unroll
  for (int i = 0; i < 4; ++i) GLL16(aSrc[i], ApkF + aUnit[i]);
  __syncthreads();
  // zero the k>=200 tail chunks of B (25..27)
  if (tid < 576) {
    int mat = tid / 96;
    int rem = tid - mat * 96;
    int chunk = 25 + (rem >> 5);
    int col = rem & 31;
    Bb[mat][chunk][col] = make_uint4(0, 0, 0, 0);
  }
  __syncthreads();

  f32x4 ai[3][2] = {};   // [gate][ct]
  f32x4 ah[3][2] = {};

  int buf = 0;
  for (int t = 0; t < NKT; ++t) {
    // prefetch next A tile into the other buffer
    if (t + 1 < NKT) {
      if (t + 1 == NKT - 1) {
        // tail tile: k 192..199 valid (chunks 0,1), rest zero; reg path
#pragma unroll
        for (int i = 0; i < 4; ++i) {
          uint4 v = make_uint4(0, 0, 0, 0);
          if (aChunk[i] < 2) v = *reinterpret_cast<const uint4*>(aSrc[i] + (NKT - 1) * KT);
          ApkF[(buf ^ 1) * 2048 + aUnit[i]] = v;
        }
      } else {
        int kt = (t + 1) * KT;
#pragma unroll
        for (int i = 0; i < 4; ++i) GLL16(aSrc[i] + kt, ApkF + (buf ^ 1) * 2048 + aUnit[i]);
      }
    }

    // frag reads + MFMA from current buffer
    int rowIdx = wv * 16 + lr;
    short8 aghi, aglo, hhi, hlo;
    unpack16(Apk[buf][0][kc * 2][rowIdx], Apk[buf][0][kc * 2 + 1][rowIdx], aghi, aglo);
    unpack16(Apk[buf][1][kc * 2][rowIdx], Apk[buf][1][kc * 2 + 1][rowIdx], hhi, hlo);
    int bchunk = t * 4 + kc;
#pragma unroll
    for (int g = 0; g < 3; ++g) {
#pragma unroll
      for (int ct = 0; ct < 2; ++ct) {
        int col = ct * 16 + lr;
        short8 b1 = *reinterpret_cast<const short8*>(&Bb[g * 2 + 0][bchunk][col]);
        short8 b2 = *reinterpret_cast<const short8*>(&Bb[g * 2 + 1][bchunk][col]);
        ai[g][ct] = __builtin_amdgcn_mfma_f32_16x16x32_bf16(aghi, b1, ai[g][ct], 0, 0, 0);
        ai[g][ct] = __builtin_amdgcn_mfma_f32_16x16x32_bf16(aglo, b1, ai[g][ct], 0, 0, 0);
        ah[g][ct] = __builtin_amdgcn_mfma_f32_16x16x32_bf16(hhi, b2, ah[g][ct], 0, 0, 0);
        ah[g][ct] = __builtin_amdgcn_mfma_f32_16x16x32_bf16(hlo, b2, ah[g][ct], 0, 0, 0);
      }
    }
    __syncthreads();   // drains gll (vmcnt) + finishes all reads of buf
    buf ^= 1;
  }

  // ---- epilogue: GRU gates, write packed hnext ----
#pragma unroll
  for (int ct = 0; ct < 2; ++ct) {
    int c = cc0 + ct * 16 + lr;
    if (c >= DIM) continue;
    float bir = b_ih[c], biz = b_ih[DIM + c], bin = b_ih[2 * DIM + c];
    float bhr = b_hh[c], bhz = b_hh[DIM + c], bhn = b_hh[2 * DIM + c];
#pragma unroll
    for (int qq = 0; qq < 4; ++qq) {
      int rr_ = row0 + wv * 16 + kc * 4 + qq;
      if (rr_ >= NN) continue;
      float gir = ai[0][ct][qq] + bir;
      float giz = ai[1][ct][qq] + biz;
      float gin = ai[2][ct][qq] + bin;
      float ghr = ah[0][ct][qq] + bhr;
      float ghz = ah[1][ct][qq] + bhz;
      float ghn = ah[2][ct][qq] + bhn;
      float rr = 1.f / (1.f + __expf(-(gir + ghr)));
      float zz = 1.f / (1.f + __expf(-(giz + ghz)));
      float nn = tanhf(gin + rr * ghn);
      float hv = up_f(hpk[(size_t)rr_ * DIM + c]);
      hnextpk[(size_t)rr_ * DIM + c] = packf((1.f - zz) * nn + zz * hv);
    }
  }
}

// ---------------- relu + segment_max pooling (packed h) ----------------
__global__ __launch_bounds__(256) void k_pool(const uint* __restrict__ hpk,
                                              const int* __restrict__ batch,
                                              float* __restrict__ pooled) {
  int i = blockIdx.x;
  int j = threadIdx.x;
  if (j < DIM) {
    int g = batch[i];
    float v = up_f(hpk[(size_t)i * DIM + j]);
    v = v > 0.f ? v : 0.f;
    atomicMax((int*)&pooled[(size_t)g * DIM + j], __float_as_int(v));
  }
}

__global__ __launch_bounds__(256) void k_classify(const float* __restrict__ pooled,
                                                  const float* __restrict__ w,
                                                  const float* __restrict__ b,
                                                  float* __restrict__ out) {
  __shared__ float r0[256], r1[256];
  int g = blockIdx.x;
  int j = threadIdx.x;
  float p = (j < DIM) ? pooled[(size_t)g * DIM + j] : 0.f;
  r0[j] = (j < DIM) ? p * w[j] : 0.f;
  r1[j] = (j < DIM) ? p * w[DIM + j] : 0.f;
  __syncthreads();
  for (int d = 128; d > 0; d >>= 1) {
    if (j < d) { r0[j] += r0[j + d]; r1[j] += r1[j + d]; }
    __syncthreads();
  }
  if (j == 0) {
    out[g * 2 + 0] = 1.f / (1.f + expf(-(r0[0] + b[0])));
    out[g * 2 + 1] = 1.f / (1.f + expf(-(r1[0] + b[1])));
  }
}

// ---------------- host ----------------
extern "C" void kernel_launch(void* const* d_in, const int* in_sizes, int n_in,
                              void* d_out, int out_size, void* d_ws, size_t ws_size,
                              hipStream_t stream) {
  const float* x = (const float*)d_in[0];
  const int* edge_index = (const int*)d_in[1];
  const int* batch = (const int*)d_in[2];
  const float* ggnn_w = (const float*)d_in[3];
  const float* w_ih = (const float*)d_in[4];
  const float* w_hh = (const float*)d_in[5];
  const float* b_ih = (const float*)d_in[6];
  const float* b_hh = (const float*)d_in[7];
  const float* cls_w = (const float*)d_in[8];
  const float* cls_b = (const float*)d_in[9];
  float* out = (float*)d_out;

  const int* src = edge_index;       // edge_index[0]
  const int* dst = edge_index + NE;  // edge_index[1]

  char* wsb = (char*)d_ws;
  size_t off = 0;
  auto alloc = [&](size_t bytes) -> void* {
    void* p = wsb + off;
    off += (bytes + 255) & ~(size_t)255;
    return p;
  };
  uint* hpkA = (uint*)alloc((size_t)NN * DIM * 4);   // 40 MB
  uint* hpkB = (uint*)alloc((size_t)NN * DIM * 4);   // 40 MB
  uint* aggpk = (uint*)alloc((size_t)NN * DIM * 4);  // 40 MB
  float* Wc_tmp = (float*)alloc((size_t)DIM * 3 * DIM * 4);
  ushort* wcB = (ushort*)alloc((size_t)NSTEPS * 3 * DIM * DIM * 2);  // 1.44 MB
  ushort* whB = (ushort*)alloc((size_t)3 * DIM * DIM * 2);           // 240 KB
  float* pooled = (float*)alloc((size_t)NG * DIM * 4);
  int* indeg = (int*)alloc((size_t)NN * 4);
  int* offs = (int*)alloc((size_t)(NN + 1) * 4);
  int* slist = (int*)alloc((size_t)NE * 4);
  if (off > ws_size) return;  // fail loud (absmax) instead of faulting

  // h0 = pack(x)
  k_pack_f32<<<2048, 256, 0, stream>>>((const float4*)x, (uint4*)hpkA, NN * DIM / 4);

  // CSR build (dst -> src list)
  k_zero_i32<<<196, 256, 0, stream>>>(indeg, NN);
  k_hist<<<(NE + 255) / 256, 256, 0, stream>>>(dst, indeg, NE);
  k_scan<<<1, 1024, 0, stream>>>(indeg, offs, NN);
  k_copy_i32<<<196, 256, 0, stream>>>(offs, indeg, NN);
  k_scatter<<<(NE + 255) / 256, 256, 0, stream>>>(dst, src, indeg, slist, NE);

  // weights: Wc[s] = ggnn_w[s] @ w_ih^T -> bf16 [600][200]; whB = bf16(w_hh)
  {
    dim3 g((3 * DIM + GBN - 1) / GBN, (DIM + GBM - 1) / GBM);
    for (int s = 0; s < NSTEPS; ++s) {
      k_gemm_bt<<<g, 256, 0, stream>>>(ggnn_w + (size_t)s * DIM * DIM, w_ih, Wc_tmp,
                                       DIM, 3 * DIM, DIM);
      k_pack_wcT<<<(600 * DIM + 255) / 256, 256, 0, stream>>>(
          Wc_tmp, wcB + (size_t)s * 3 * DIM * DIM);
    }
    k_pack_bf<<<512, 256, 0, stream>>>(w_hh, whB, 3 * DIM * DIM);
  }

  uint* hcur = hpkA;
  uint* hnext = hpkB;
  for (int s = 0; s < NSTEPS; ++s) {
    k_aggregate_pk<<<(NN + 3) / 4, 256, 0, stream>>>(hcur, offs, slist, aggpk);
    k_fused_mfma<<<NRB * NCB, NT, 0, stream>>>(aggpk, hcur,
                                               wcB + (size_t)s * 3 * DIM * DIM,
                                               whB, b_ih, b_hh, hnext);
    uint* t = hcur; hcur = hnext; hnext = t;
  }

  k_zero_f32<<<200, 256, 0, stream>>>(pooled, NG * DIM);
  k_pool<<<NN, 256, 0, stream>>>(hcur, batch, pooled);
  k_classify<<<NG, 256, 0, stream>>>(pooled, cls_w, cls_b, out);
}

// Round 7
// 1262.722 us; speedup vs baseline: 3.8896x; 1.2991x over previous
//
#include <hip/hip_runtime.h>
#include <cstdint>
#include <cstddef>

#define NN 50000
#define NE 400000
#define NG 256
#define DIM 200
#define NSTEPS 6

typedef unsigned int uint;
typedef unsigned short ushort;
typedef __attribute__((ext_vector_type(8))) short short8;
typedef __attribute__((ext_vector_type(4))) float f32x4;

#define GLL16(gsrc, ldst)                                                        \
  __builtin_amdgcn_global_load_lds(                                              \
      (const __attribute__((address_space(1))) void*)(gsrc),                     \
      (__attribute__((address_space(3))) void*)(ldst), 16, 0, 0)

// ---- packed split-bf16 helpers: word = (hi_bf16 << 16) | lo_bf16 ----
__device__ __forceinline__ float up_hi(uint w) { return __uint_as_float(w & 0xffff0000u); }
__device__ __forceinline__ float up_lo(uint w) { return __uint_as_float(w << 16); }
__device__ __forceinline__ float up_f(uint w) { return up_hi(w) + up_lo(w); }
__device__ __forceinline__ uint packf(float v) {
  uint u = __float_as_uint(v);
  uint t = u + 0x7fffu + ((u >> 16) & 1u);   // RN-even to bf16
  uint hb = t & 0xffff0000u;
  float lo = v - __uint_as_float(hb);
  uint ul = __float_as_uint(lo);
  uint t2 = ul + 0x7fffu + ((ul >> 16) & 1u);
  return hb | (t2 >> 16);
}
__device__ __forceinline__ ushort bf16rn(float v) {
  uint u = __float_as_uint(v);
  return (ushort)((u + 0x7fffu + ((u >> 16) & 1u)) >> 16);
}

// ---------------- utility kernels ----------------
__global__ void k_zero_i32(int* __restrict__ p, int n) {
  for (int i = blockIdx.x * blockDim.x + threadIdx.x; i < n; i += gridDim.x * blockDim.x)
    p[i] = 0;
}
__global__ void k_zero_f32(float* __restrict__ p, int n) {
  for (int i = blockIdx.x * blockDim.x + threadIdx.x; i < n; i += gridDim.x * blockDim.x)
    p[i] = 0.f;
}
__global__ void k_copy_i32(const int* __restrict__ a, int* __restrict__ b, int n) {
  for (int i = blockIdx.x * blockDim.x + threadIdx.x; i < n; i += gridDim.x * blockDim.x)
    b[i] = a[i];
}
__global__ void k_hist(const int* __restrict__ dst, int* __restrict__ cnt, int nE) {
  int e = blockIdx.x * blockDim.x + threadIdx.x;
  if (e < nE) atomicAdd(&cnt[dst[e]], 1);
}
__global__ void k_scan(const int* __restrict__ cnt, int* __restrict__ off, int n) {
  __shared__ int buf[1024];
  __shared__ int carry;
  int tid = threadIdx.x;
  if (tid == 0) { carry = 0; off[0] = 0; }
  __syncthreads();
  for (int base = 0; base < n; base += 1024) {
    int i = base + tid;
    int v = (i < n) ? cnt[i] : 0;
    buf[tid] = v;
    __syncthreads();
    for (int d = 1; d < 1024; d <<= 1) {
      int t = (tid >= d) ? buf[tid - d] : 0;
      __syncthreads();
      buf[tid] += t;
      __syncthreads();
    }
    if (i < n) off[i + 1] = carry + buf[tid];
    __syncthreads();
    if (tid == 0) carry += buf[1023];
    __syncthreads();
  }
}
__global__ void k_scatter(const int* __restrict__ dst, const int* __restrict__ src,
                          int* __restrict__ cursor, int* __restrict__ slist, int nE) {
  int e = blockIdx.x * blockDim.x + threadIdx.x;
  if (e < nE) {
    int d = dst[e];
    int pos = atomicAdd(&cursor[d], 1);
    slist[pos] = src[e];
  }
}

// pack fp32 array -> packed split-bf16 (vectorized)
__global__ void k_pack_f32(const float4* __restrict__ in, uint4* __restrict__ out, int n4) {
  for (int i = blockIdx.x * blockDim.x + threadIdx.x; i < n4; i += gridDim.x * blockDim.x) {
    float4 v = in[i];
    uint4 o;
    o.x = packf(v.x); o.y = packf(v.y); o.z = packf(v.z); o.w = packf(v.w);
    out[i] = o;
  }
}

// elementwise fp32 -> bf16 ushort
__global__ void k_pack_bf(const float* __restrict__ in, ushort* __restrict__ out, int n) {
  for (int i = blockIdx.x * blockDim.x + threadIdx.x; i < n; i += gridDim.x * blockDim.x)
    out[i] = bf16rn(in[i]);
}

// transpose+pack: Wc fp32 [200][600] -> bf16 ushort [600][200]
__global__ void k_pack_wcT(const float* __restrict__ Wc, ushort* __restrict__ out) {
  int idx = blockIdx.x * blockDim.x + threadIdx.x;
  if (idx < 600 * DIM) {
    int c = idx / DIM, k = idx - c * DIM;
    out[idx] = bf16rn(Wc[(size_t)k * 600 + c]);
  }
}

// ---------------- fp32 GEMM (tiny, for Wc = W @ w_ih^T) ----------------
#define GBM 64
#define GBN 64
#define GBK 8
__global__ __launch_bounds__(256) void k_gemm_bt(const float* __restrict__ A,
                                                 const float* __restrict__ B,
                                                 float* __restrict__ C,
                                                 int M, int N, int K) {
  __shared__ __align__(16) float As[GBK][GBM];
  __shared__ __align__(16) float Bs[GBK][GBN];
  int tid = threadIdx.x;
  int row0 = blockIdx.y * GBM;
  int col0 = blockIdx.x * GBN;
  int ty = tid >> 4, tx = tid & 15;
  float acc[4][4] = {};
  for (int k0 = 0; k0 < K; k0 += GBK) {
    {
      int r = tid >> 2;
      int kk = (tid & 3) * 2;
      int gr = row0 + r;
      float2 v = make_float2(0.f, 0.f);
      if (gr < M) v = *reinterpret_cast<const float2*>(&A[(size_t)gr * K + k0 + kk]);
      As[kk][r] = v.x; As[kk + 1][r] = v.y;
    }
    {
      int n = tid >> 2;
      int kk = (tid & 3) * 2;
      int gn = col0 + n;
      float2 v = make_float2(0.f, 0.f);
      if (gn < N) v = *reinterpret_cast<const float2*>(&B[(size_t)gn * K + k0 + kk]);
      Bs[kk][n] = v.x; Bs[kk + 1][n] = v.y;
    }
    __syncthreads();
#pragma unroll
    for (int k = 0; k < GBK; ++k) {
      float4 av = *reinterpret_cast<const float4*>(&As[k][ty * 4]);
      float4 bv = *reinterpret_cast<const float4*>(&Bs[k][tx * 4]);
      float a[4] = {av.x, av.y, av.z, av.w};
      float b[4] = {bv.x, bv.y, bv.z, bv.w};
#pragma unroll
      for (int i = 0; i < 4; ++i)
#pragma unroll
        for (int j = 0; j < 4; ++j) acc[i][j] += a[i] * b[j];
    }
    __syncthreads();
  }
#pragma unroll
  for (int i = 0; i < 4; ++i) {
    int r = row0 + ty * 4 + i;
    if (r >= M) continue;
#pragma unroll
    for (int j = 0; j < 4; ++j) {
      int c = col0 + tx * 4 + j;
      if (c < N) C[(size_t)r * N + c] = acc[i][j];
    }
  }
}

// ---------------- aggregation: wave per node, uint4 per lane ----------------
__global__ __launch_bounds__(256) void k_aggregate_pk(const uint* __restrict__ hpk,
                                                      const int* __restrict__ off,
                                                      const int* __restrict__ slist,
                                                      uint* __restrict__ aggpk) {
  int node = blockIdx.x * 4 + (threadIdx.x >> 6);
  if (node >= NN) return;
  int lane = threadIdx.x & 63;
  int c4 = lane * 4;
  bool act = c4 < DIM;
  float a0 = 0.f, a1 = 0.f, a2 = 0.f, a3 = 0.f;
  int beg = off[node], end = off[node + 1];
  int p = beg;
  for (; p + 1 < end; p += 2) {
    int s0 = slist[p];
    int s1 = slist[p + 1];
    if (act) {
      uint4 u0 = *reinterpret_cast<const uint4*>(hpk + (size_t)s0 * DIM + c4);
      uint4 u1 = *reinterpret_cast<const uint4*>(hpk + (size_t)s1 * DIM + c4);
      a0 += up_f(u0.x) + up_f(u1.x);
      a1 += up_f(u0.y) + up_f(u1.y);
      a2 += up_f(u0.z) + up_f(u1.z);
      a3 += up_f(u0.w) + up_f(u1.w);
    }
  }
  if (p < end) {
    int s = slist[p];
    if (act) {
      uint4 u = *reinterpret_cast<const uint4*>(hpk + (size_t)s * DIM + c4);
      a0 += up_f(u.x); a1 += up_f(u.y); a2 += up_f(u.z); a3 += up_f(u.w);
    }
  }
  if (act) {
    uint4 o;
    o.x = packf(a0); o.y = packf(a1); o.z = packf(a2); o.w = packf(a3);
    *reinterpret_cast<uint4*>(aggpk + (size_t)node * DIM + c4) = o;
  }
}

// ---------------- fused MFMA GRU step (barrier-free persistent) ----------
// Block: 256 thr (4 waves). B (6 mats x 25 chunks x 32 cols) resident in LDS
// (75KB -> 2 blocks/CU). A loaded per-lane global->reg, dbuf prefetch,
// split-bf16 exact. Block loops over 11 row-panels of 64 rows; ONE barrier.
#define NPAN 782            // ceil(NN/64)
#define PPC 11              // panels per chunk
#define NCHK 73             // chunks (73*11 = 803 >= 782)
#define GRIDF 511           // 7 cols * 73 chunks

__device__ __forceinline__ void unpack16(const uint4 p0, const uint4 p1,
                                         short8& hi, short8& lo) {
  union U { uint u[4]; short8 s; };
  U H, L;
  H.u[0] = (p0.x >> 16) | (p0.y & 0xffff0000u);
  H.u[1] = (p0.z >> 16) | (p0.w & 0xffff0000u);
  H.u[2] = (p1.x >> 16) | (p1.y & 0xffff0000u);
  H.u[3] = (p1.z >> 16) | (p1.w & 0xffff0000u);
  L.u[0] = (p0.x & 0xffffu) | (p0.y << 16);
  L.u[1] = (p0.z & 0xffffu) | (p0.w << 16);
  L.u[2] = (p1.x & 0xffffu) | (p1.y << 16);
  L.u[3] = (p1.z & 0xffffu) | (p1.w << 16);
  hi = H.s; lo = L.s;
}

#define MFMA16(a, b, c) __builtin_amdgcn_mfma_f32_16x16x32_bf16(a, b, c, 0, 0, 0)

__global__ __launch_bounds__(256, 2) void k_fused_mfma(
    const uint* __restrict__ aggpk, const uint* __restrict__ hpk,
    const ushort* __restrict__ wcB, const ushort* __restrict__ whB,
    const float* __restrict__ b_ih, const float* __restrict__ b_hh,
    uint* __restrict__ hnextpk) {
  __shared__ uint4 Bb[6][25][32];   // 75 KB

  int tid = threadIdx.x;
  int lane = tid & 63;
  int wv = tid >> 6;          // 0..3
  int lr = lane & 15;
  int kc = lane >> 4;         // 0..3

  // XCD-aware bijective swizzle (m204, nwg=511: q=63, r=7)
  int x = blockIdx.x & 7, ii = blockIdx.x >> 3;
  int work = (x < 7 ? x * 64 : 448) + ii;
  int chunk = work / 7;
  int col = work - chunk * 7;
  int cc0 = col * 32;
  if (chunk * PPC >= NPAN) return;

  // ---- stage B once (gll), clamp source col to 199 for the 224-pad tail ----
  {
    uint4* BbF = &Bb[0][0][0];
    for (int i2 = 0; i2 < 19; ++i2) {
      int u = tid + i2 * 256;
      if (u < 4800) {             // wave-uniform at the boundary
        int mat = u / 800;        // 25*32 per mat
        int rem = u - mat * 800;
        int ch = rem >> 5;
        int c = rem & 31;
        int gc = cc0 + c; if (gc > 199) gc = 199;   // stay in-bounds
        const ushort* wsrc = (mat & 1) ? whB : wcB;
        const ushort* sp = wsrc + (size_t)((mat >> 1) * DIM + gc) * DIM + ch * 8;
        GLL16(sp, BbF + u);
      }
    }
  }
  __syncthreads();   // the ONLY block-wide barrier

  for (int j = 0; j < PPC; ++j) {
    int p = chunk * PPC + j;
    if (p >= NPAN) break;
    int prow0 = p * 64;
    int rw = prow0 + wv * 16 + lr;           // this lane's A-fragment row
    int rcl = rw < NN ? rw : NN - 1;
    const uint* arow = aggpk + (size_t)rcl * DIM;
    const uint* hrow = hpk + (size_t)rcl * DIM;
    int k0 = kc * 8;

    f32x4 ai[3][2] = {};
    f32x4 ah[3][2] = {};
    uint4 aq[2][2], hq[2][2];
    aq[0][0] = *reinterpret_cast<const uint4*>(arow + k0);
    aq[0][1] = *reinterpret_cast<const uint4*>(arow + k0 + 4);
    hq[0][0] = *reinterpret_cast<const uint4*>(hrow + k0);
    hq[0][1] = *reinterpret_cast<const uint4*>(hrow + k0 + 4);

#pragma unroll
    for (int t = 0; t < 7; ++t) {
      const int cur = t & 1, nxt = cur ^ 1;
      if (t < 6) {
        if (t == 5) {   // tile 6 tail: only kc==0 (k 192-199) valid
          bool vld = (kc == 0);
          uint4 z = make_uint4(0, 0, 0, 0);
          aq[nxt][0] = vld ? *reinterpret_cast<const uint4*>(arow + 192) : z;
          aq[nxt][1] = vld ? *reinterpret_cast<const uint4*>(arow + 196) : z;
          hq[nxt][0] = vld ? *reinterpret_cast<const uint4*>(hrow + 192) : z;
          hq[nxt][1] = vld ? *reinterpret_cast<const uint4*>(hrow + 196) : z;
        } else {
          int ko = (t + 1) * 32 + k0;
          aq[nxt][0] = *reinterpret_cast<const uint4*>(arow + ko);
          aq[nxt][1] = *reinterpret_cast<const uint4*>(arow + ko + 4);
          hq[nxt][0] = *reinterpret_cast<const uint4*>(hrow + ko);
          hq[nxt][1] = *reinterpret_cast<const uint4*>(hrow + ko + 4);
        }
      }
      short8 aghi, aglo, hhi, hlo;
      unpack16(aq[cur][0], aq[cur][1], aghi, aglo);
      unpack16(hq[cur][0], hq[cur][1], hhi, hlo);
      int bch = t * 4 + kc; if (bch > 24) bch = 24;   // clamped rows x A=0
#pragma unroll
      for (int g = 0; g < 3; ++g) {
#pragma unroll
        for (int ct = 0; ct < 2; ++ct) {
          short8 b1 = *reinterpret_cast<const short8*>(&Bb[g * 2 + 0][bch][ct * 16 + lr]);
          short8 b2 = *reinterpret_cast<const short8*>(&Bb[g * 2 + 1][bch][ct * 16 + lr]);
          ai[g][ct] = MFMA16(aghi, b1, ai[g][ct]);
          ai[g][ct] = MFMA16(aglo, b1, ai[g][ct]);
          ah[g][ct] = MFMA16(hhi, b2, ah[g][ct]);
          ah[g][ct] = MFMA16(hlo, b2, ah[g][ct]);
        }
      }
    }

    // ---- epilogue: GRU gates for this panel's 16x32 wave-tile ----
    uint hvw[2][4];
#pragma unroll
    for (int qq = 0; qq < 4; ++qq) {
      int r_ = prow0 + wv * 16 + kc * 4 + qq;
      int rc = r_ < NN ? r_ : NN - 1;
#pragma unroll
      for (int ct = 0; ct < 2; ++ct) {
        int c = cc0 + ct * 16 + lr; if (c > 199) c = 199;
        hvw[ct][qq] = hpk[(size_t)rc * DIM + c];
      }
    }
#pragma unroll
    for (int ct = 0; ct < 2; ++ct) {
      int c = cc0 + ct * 16 + lr;
      if (c >= DIM) continue;
      float bir = b_ih[c], biz = b_ih[DIM + c], bin = b_ih[2 * DIM + c];
      float bhr = b_hh[c], bhz = b_hh[DIM + c], bhn = b_hh[2 * DIM + c];
#pragma unroll
      for (int qq = 0; qq < 4; ++qq) {
        int r_ = prow0 + wv * 16 + kc * 4 + qq;
        if (r_ >= NN) continue;
        float gir = ai[0][ct][qq] + bir;
        float giz = ai[1][ct][qq] + biz;
        float gin = ai[2][ct][qq] + bin;
        float ghr = ah[0][ct][qq] + bhr;
        float ghz = ah[1][ct][qq] + bhz;
        float ghn = ah[2][ct][qq] + bhn;
        float rr = 1.f / (1.f + __expf(-(gir + ghr)));
        float zz = 1.f / (1.f + __expf(-(giz + ghz)));
        float nn = tanhf(gin + rr * ghn);
        float hv = up_f(hvw[ct][qq]);
        hnextpk[(size_t)r_ * DIM + c] = packf((1.f - zz) * nn + zz * hv);
      }
    }
  }
}

// ---------------- relu + segment_max pooling (packed h) ----------------
__global__ __launch_bounds__(256) void k_pool(const uint* __restrict__ hpk,
                                              const int* __restrict__ batch,
                                              float* __restrict__ pooled) {
  int i = blockIdx.x;
  int j = threadIdx.x;
  if (j < DIM) {
    int g = batch[i];
    float v = up_f(hpk[(size_t)i * DIM + j]);
    v = v > 0.f ? v : 0.f;
    atomicMax((int*)&pooled[(size_t)g * DIM + j], __float_as_int(v));
  }
}

__global__ __launch_bounds__(256) void k_classify(const float* __restrict__ pooled,
                                                  const float* __restrict__ w,
                                                  const float* __restrict__ b,
                                                  float* __restrict__ out) {
  __shared__ float r0[256], r1[256];
  int g = blockIdx.x;
  int j = threadIdx.x;
  float p = (j < DIM) ? pooled[(size_t)g * DIM + j] : 0.f;
  r0[j] = (j < DIM) ? p * w[j] : 0.f;
  r1[j] = (j < DIM) ? p * w[DIM + j] : 0.f;
  __syncthreads();
  for (int d = 128; d > 0; d >>= 1) {
    if (j < d) { r0[j] += r0[j + d]; r1[j] += r1[j + d]; }
    __syncthreads();
  }
  if (j == 0) {
    out[g * 2 + 0] = 1.f / (1.f + expf(-(r0[0] + b[0])));
    out[g * 2 + 1] = 1.f / (1.f + expf(-(r1[0] + b[1])));
  }
}

// ---------------- host ----------------
extern "C" void kernel_launch(void* const* d_in, const int* in_sizes, int n_in,
                              void* d_out, int out_size, void* d_ws, size_t ws_size,
                              hipStream_t stream) {
  const float* x = (const float*)d_in[0];
  const int* edge_index = (const int*)d_in[1];
  const int* batch = (const int*)d_in[2];
  const float* ggnn_w = (const float*)d_in[3];
  const float* w_ih = (const float*)d_in[4];
  const float* w_hh = (const float*)d_in[5];
  const float* b_ih = (const float*)d_in[6];
  const float* b_hh = (const float*)d_in[7];
  const float* cls_w = (const float*)d_in[8];
  const float* cls_b = (const float*)d_in[9];
  float* out = (float*)d_out;

  const int* src = edge_index;       // edge_index[0]
  const int* dst = edge_index + NE;  // edge_index[1]

  char* wsb = (char*)d_ws;
  size_t off = 0;
  auto alloc = [&](size_t bytes) -> void* {
    void* p = wsb + off;
    off += (bytes + 255) & ~(size_t)255;
    return p;
  };
  uint* hpkA = (uint*)alloc((size_t)NN * DIM * 4);   // 40 MB
  uint* hpkB = (uint*)alloc((size_t)NN * DIM * 4);   // 40 MB
  uint* aggpk = (uint*)alloc((size_t)NN * DIM * 4);  // 40 MB
  float* Wc_tmp = (float*)alloc((size_t)DIM * 3 * DIM * 4);
  ushort* wcB = (ushort*)alloc((size_t)NSTEPS * 3 * DIM * DIM * 2);  // 1.44 MB
  ushort* whB = (ushort*)alloc((size_t)3 * DIM * DIM * 2);           // 240 KB
  float* pooled = (float*)alloc((size_t)NG * DIM * 4);
  int* indeg = (int*)alloc((size_t)NN * 4);
  int* offs = (int*)alloc((size_t)(NN + 1) * 4);
  int* slist = (int*)alloc((size_t)NE * 4);
  if (off > ws_size) return;  // fail loud (absmax) instead of faulting

  // h0 = pack(x)
  k_pack_f32<<<2048, 256, 0, stream>>>((const float4*)x, (uint4*)hpkA, NN * DIM / 4);

  // CSR build (dst -> src list)
  k_zero_i32<<<196, 256, 0, stream>>>(indeg, NN);
  k_hist<<<(NE + 255) / 256, 256, 0, stream>>>(dst, indeg, NE);
  k_scan<<<1, 1024, 0, stream>>>(indeg, offs, NN);
  k_copy_i32<<<196, 256, 0, stream>>>(offs, indeg, NN);
  k_scatter<<<(NE + 255) / 256, 256, 0, stream>>>(dst, src, indeg, slist, NE);

  // weights: Wc[s] = ggnn_w[s] @ w_ih^T -> bf16 [600][200]; whB = bf16(w_hh)
  {
    dim3 g((3 * DIM + GBN - 1) / GBN, (DIM + GBM - 1) / GBM);
    for (int s = 0; s < NSTEPS; ++s) {
      k_gemm_bt<<<g, 256, 0, stream>>>(ggnn_w + (size_t)s * DIM * DIM, w_ih, Wc_tmp,
                                       DIM, 3 * DIM, DIM);
      k_pack_wcT<<<(600 * DIM + 255) / 256, 256, 0, stream>>>(
          Wc_tmp, wcB + (size_t)s * 3 * DIM * DIM);
    }
    k_pack_bf<<<512, 256, 0, stream>>>(w_hh, whB, 3 * DIM * DIM);
  }

  uint* hcur = hpkA;
  uint* hnext = hpkB;
  for (int s = 0; s < NSTEPS; ++s) {
    k_aggregate_pk<<<(NN + 3) / 4, 256, 0, stream>>>(hcur, offs, slist, aggpk);
    k_fused_mfma<<<GRIDF, 256, 0, stream>>>(aggpk, hcur,
                                            wcB + (size_t)s * 3 * DIM * DIM,
                                            whB, b_ih, b_hh, hnext);
    uint* t = hcur; hcur = hnext; hnext = t;
  }

  k_zero_f32<<<200, 256, 0, stream>>>(pooled, NG * DIM);
  k_pool<<<NN, 256, 0, stream>>>(hcur, batch, pooled);
  k_classify<<<NG, 256, 0, stream>>>(pooled, cls_w, cls_b, out);
}